// Round 8
// baseline (81.928 us; speedup 1.0000x reference)
//
#include <hip/hip_runtime.h>

// KGCN forward, MI355X. 8 waves/block (512 thr), one wave per batch element.
// R8 insight: the LDS pipe is CU-shared while VALU is per-SIMD x4 -- R7 was
// LDS-throughput-bound (160 broadcast b128 reads/elem in the matvec phase).
// Fix: broadcast pre[k] via v_readlane (VALU, SGPR operand) instead of LDS;
// s_pre is deleted, pre/h rows live in registers (statically indexed).
// LDS keeps only the staged W (swizzled) and rel^T tables: 33 KB.

namespace {

constexpr int kDim      = 64;
constexpr int kNN       = 8;
constexpr int kNumEnt   = 100000;
constexpr int kItemInKG = 20000;
constexpr int kElems    = 8;     // batch elements (waves) per block
constexpr int kVecs     = 9;     // pre0 + 8x pre1 rows per element
constexpr int kRelChunks = 976;  // 61 rel rows * 16 float4 chunks

__device__ __forceinline__ float fast_sigmoid(float x) {
  return 1.0f / (1.0f + __expf(-x));
}
__device__ __forceinline__ float fast_tanh(float x) {
  return 2.0f / (1.0f + __expf(-2.0f * x)) - 1.0f;
}
__device__ __forceinline__ float readlane_f(float v, int lane) {
  return __int_as_float(__builtin_amdgcn_readlane(__float_as_int(v), lane));
}

__global__ void __launch_bounds__(kElems * 64)
kgcn_kernel(const int* __restrict__ u, const int* __restrict__ v,
            const float* __restrict__ usr_emb, const float* __restrict__ item_emb,
            const float* __restrict__ ent_emb, const float* __restrict__ rel_emb,
            const float* __restrict__ W, const float* __restrict__ bias,
            const int* __restrict__ adj_ent, const int* __restrict__ adj_rel,
            float* __restrict__ out)
{
  const int tid = threadIdx.x;
  const int wv  = tid >> 6;
  const int ln  = tid & 63;
  const int b   = blockIdx.x * kElems + wv;

  __shared__ float4 s_w4[kDim * 16];     // 16,384 B (chunk-XOR swizzled)
  __shared__ float  s_relt[kDim * 65];   // 16,640 B (rel^T, stride 65)

  // ---- staging loads (coalesced float4) ----
  const float4* W4 = reinterpret_cast<const float4*>(W);
  const float4* R4 = reinterpret_cast<const float4*>(rel_emb);
  const float4 wst0 = W4[tid];
  const float4 wst1 = W4[512 + tid];
  const float4 rst0 = R4[tid];                   // 512 < 976: in range
  const float4 rst1 = (512 + tid < kRelChunks) ? R4[512 + tid]
                                               : make_float4(0.f, 0.f, 0.f, 0.f);

  // ---- adjacency chain (registers + cross-lane only) ----
  const int   uid = u[b];
  const int   vid = v[b];
  const float ue  = usr_emb[(size_t)uid * kDim + ln];
  const float ev0 = item_emb[(size_t)vid * kDim + ln];
  const int   e0  = (vid >= kItemInKG) ? kNumEnt : vid;   // pad entity

  int e1v = 0, r1v = 0;
  if (ln < kNN) {
    e1v = adj_ent[(size_t)e0 * kNN + ln];
    r1v = adj_rel[(size_t)e0 * kNN + ln];
  }
  const int parent = __shfl(e1v, ln >> 3, 64);   // sources are lanes 0..7
  const int e2v    = adj_ent[(size_t)parent * kNN + (ln & 7)];
  const int r2v    = adj_rel[(size_t)parent * kNN + (ln & 7)];

  // ---- staging writes ----
  {
    // W: chunk-XOR swizzle; read back at (k4&8)|((k4^ln)&7) -> natural order.
    int id = tid, row = id >> 4, col = id & 15;
    s_w4[(row << 4) | (col & 8) | ((col ^ row) & 7)] = wst0;
    id = 512 + tid; row = id >> 4; col = id & 15;
    s_w4[(row << 4) | (col & 8) | ((col ^ row) & 7)] = wst1;
  }
  {
    // rel transposed: s_relt[k*65 + r] = rel[r][k]; write banks 2-way = free.
    int id = tid, r = id >> 4, c = (id & 15) << 2;
    s_relt[(c + 0) * 65 + r] = rst0.x;
    s_relt[(c + 1) * 65 + r] = rst0.y;
    s_relt[(c + 2) * 65 + r] = rst0.z;
    s_relt[(c + 3) * 65 + r] = rst0.w;
    id = 512 + tid; r = id >> 4; c = (id & 15) << 2;  // rows 61..63: zeros
    s_relt[(c + 0) * 65 + r] = rst1.x;
    s_relt[(c + 1) * 65 + r] = rst1.y;
    s_relt[(c + 2) * 65 + r] = rst1.z;
    s_relt[(c + 3) * 65 + r] = rst1.w;
  }

  // ---- hop-1 embedding gathers (ids wave-uniform via readlane -> saddr) ----
  float ev1r[kNN];
  #pragma unroll
  for (int m = 0; m < kNN; ++m)
    ev1r[m] = ent_emb[(size_t)__builtin_amdgcn_readlane(e1v, m) * kDim + ln];

  __syncthreads();   // staging visible

  // ---- t[r] = dot(ue, rel_emb[r]), lane = r. Column reads: 2-way = free. ----
  float t;
  {
    const float* relc = &s_relt[ln];
    float a0 = 0.f, a1 = 0.f, a2 = 0.f, a3 = 0.f;
    #pragma unroll
    for (int k = 0; k < kDim; k += 4) {
      a0 = fmaf(readlane_f(ue, k + 0), relc[(k + 0) * 65], a0);
      a1 = fmaf(readlane_f(ue, k + 1), relc[(k + 1) * 65], a1);
      a2 = fmaf(readlane_f(ue, k + 2), relc[(k + 2) * 65], a2);
      a3 = fmaf(readlane_f(ue, k + 3), relc[(k + 3) * 65], a3);
    }
    t = (a0 + a1) + (a2 + a3);
  }

  // ---- softmaxes: score = bpermute lookup of t; 8-lane groups {1,2,4} ----
  float w2v;   // hop-2 weight for pair (m = ln>>3, n = ln&7)
  {
    const float s2 = __shfl(t, r2v, 64);
    float mx = s2;
    #pragma unroll
    for (int m = 1; m <= 4; m <<= 1) mx = fmaxf(mx, __shfl_xor(mx, m, 64));
    const float e = __expf(s2 - mx);
    float sm = e;
    #pragma unroll
    for (int m = 1; m <= 4; m <<= 1) sm += __shfl_xor(sm, m, 64);
    w2v = e / sm;
  }
  float w0v;   // hop-0 weight, valid on lanes 0..7 (reused for iter-1)
  {
    const float s0 = __shfl(t, r1v, 64);
    float mx = s0;
    #pragma unroll
    for (int m = 1; m <= 4; m <<= 1) mx = fmaxf(mx, __shfl_xor(mx, m, 64));
    w0v = __expf(s0 - mx);
    float sm = w0v;
    #pragma unroll
    for (int m = 1; m <= 4; m <<= 1) sm += __shfl_xor(sm, m, 64);
    w0v /= sm;
  }

  // ---- aggregation (lane = dim), results in REGISTERS ----
  float pre[kVecs];
  {
    float agg = 0.f;
    #pragma unroll
    for (int n = 0; n < kNN; ++n)
      agg = fmaf(readlane_f(w0v, n), ev1r[n], agg);
    pre[0] = ev0 + agg;
  }
  // rows 1..8: gathers inline, unroll 2 (no prefetch arrays -- R5 lesson).
  #pragma unroll 2
  for (int m = 0; m < kNN; ++m) {
    float acc = 0.f;
    #pragma unroll
    for (int n = 0; n < kNN; ++n) {
      const int e2u = __builtin_amdgcn_readlane(e2v, m * kNN + n);
      acc = fmaf(readlane_f(w2v, m * kNN + n),
                 ent_emb[(size_t)e2u * kDim + ln], acc);
    }
    pre[1 + m] = ev1r[m] + acc;
  }

  // ---- Wreg: ONE swizzled 16-read pass -> natural-order W[ln] row ----
  float4 Wreg[16];
  #pragma unroll
  for (int k4 = 0; k4 < 16; ++k4)
    Wreg[k4] = s_w4[(ln << 4) | (k4 & 8) | ((k4 ^ ln) & 7)];

  const float bln = bias[ln];

  // ---- 9 matvecs: p[k] broadcast via v_readlane (VALU pipe, zero LDS) ----
  float h[kVecs];
  #pragma unroll
  for (int m = 0; m < kVecs; ++m) {
    float a0 = 0.f, a1 = 0.f, a2 = 0.f, a3 = 0.f;
    #pragma unroll
    for (int q = 0; q < 16; ++q) {
      a0 = fmaf(readlane_f(pre[m], 4 * q + 0), Wreg[q].x, a0);
      a1 = fmaf(readlane_f(pre[m], 4 * q + 1), Wreg[q].y, a1);
      a2 = fmaf(readlane_f(pre[m], 4 * q + 2), Wreg[q].z, a2);
      a3 = fmaf(readlane_f(pre[m], 4 * q + 3), Wreg[q].w, a3);
    }
    h[m] = fast_sigmoid(((a0 + a1) + (a2 + a3)) + bln);   // iter 0 -> sigmoid
  }

  // ---- iter-1 hop-0 (same ue, same rels -> reuse w0), registers only ----
  float p0f = h[0];
  #pragma unroll
  for (int n = 0; n < kNN; ++n)
    p0f = fmaf(readlane_f(w0v, n), h[1 + n], p0f);

  // ---- final matvec + tanh + user dot ----
  {
    float a0 = 0.f, a1 = 0.f, a2 = 0.f, a3 = 0.f;
    #pragma unroll
    for (int q = 0; q < 16; ++q) {
      a0 = fmaf(readlane_f(p0f, 4 * q + 0), Wreg[q].x, a0);
      a1 = fmaf(readlane_f(p0f, 4 * q + 1), Wreg[q].y, a1);
      a2 = fmaf(readlane_f(p0f, 4 * q + 2), Wreg[q].z, a2);
      a3 = fmaf(readlane_f(p0f, 4 * q + 3), Wreg[q].w, a3);
    }
    const float item = fast_tanh(((a0 + a1) + (a2 + a3)) + bln);
    float tt = ue * item;
    #pragma unroll
    for (int off = 32; off > 0; off >>= 1)
      tt += __shfl_xor(tt, off, 64);
    if (ln == 0) out[b] = fast_sigmoid(tt);
  }
}

}  // namespace

extern "C" void kernel_launch(void* const* d_in, const int* in_sizes, int n_in,
                              void* d_out, int out_size, void* d_ws, size_t ws_size,
                              hipStream_t stream) {
  const int*   u        = (const int*)d_in[0];
  const int*   v        = (const int*)d_in[1];
  const float* usr_emb  = (const float*)d_in[2];
  const float* item_emb = (const float*)d_in[3];
  const float* ent_emb  = (const float*)d_in[4];
  const float* rel_emb  = (const float*)d_in[5];
  const float* W        = (const float*)d_in[6];
  const float* bias     = (const float*)d_in[7];
  const int*   adj_ent  = (const int*)d_in[8];
  const int*   adj_rel  = (const int*)d_in[9];
  float*       out      = (float*)d_out;

  const int B = in_sizes[0];   // 16384, divisible by kElems=8
  dim3 grid(B / kElems), block(kElems * 64);
  hipLaunchKernelGGL(kgcn_kernel, grid, block, 0, stream,
                     u, v, usr_emb, item_emb, ent_emb, rel_emb, W, bias,
                     adj_ent, adj_rel, out);
}

// Round 9
// 66.301 us; speedup vs baseline: 1.2357x; 1.2357x over previous
//
#include <hip/hip_runtime.h>
#include <hip/hip_fp16.h>

// KGCN forward, MI355X. R9: the R4/R7 plateau (~67us) matches FETCH_SIZE/2.2TB/s
// -- the kernel is HBM-random-gather bound (ent_emb 256B rows, 16% per-XCD L2
// hit). Fix: pre-pass converts ent_emb fp32->fp16 into d_ws (12.8MB table,
// 128B rows) -> ~half the gather traffic + better L2 residency.
// Also: v_pk_fma_f32 (packed fp32) in the matvecs (640->320 issues/wave) so
// VALU doesn't become the wall. Matvec p-operands stay LDS broadcasts (R8
// proved readlane-broadcast costs more than LDS).

namespace {

constexpr int kDim      = 64;
constexpr int kNN       = 8;
constexpr int kNumEnt   = 100000;
constexpr int kItemInKG = 20000;
constexpr int kElems    = 8;     // batch elements (waves) per block
constexpr int kVecs     = 9;     // pre0 + 8x pre1 rows per element
constexpr int kRelChunks = 976;  // 61 rel rows * 16 float4 chunks
constexpr size_t kEntHalfBytes = (size_t)(kNumEnt + 1) * kDim * sizeof(__half);

typedef float v2f __attribute__((ext_vector_type(2)));

__device__ __forceinline__ float fast_sigmoid(float x) {
  return 1.0f / (1.0f + __expf(-x));
}
__device__ __forceinline__ float fast_tanh(float x) {
  return 2.0f / (1.0f + __expf(-2.0f * x)) - 1.0f;
}
__device__ __forceinline__ float readlane_f(float v, int lane) {
  return __int_as_float(__builtin_amdgcn_readlane(__float_as_int(v), lane));
}
// packed fp32 FMA: acc = a*b + acc (2 lanes-worth per issue)
__device__ __forceinline__ void pk_fma(v2f& acc, v2f a, v2f b) {
  asm("v_pk_fma_f32 %0, %1, %2, %0" : "+v"(acc) : "v"(a), "v"(b));
}

// ---- pre-pass: ent_emb fp32 -> fp16 into workspace ----
__global__ void __launch_bounds__(256)
conv_kernel(const float* __restrict__ src, __half2* __restrict__ dst, int n4) {
  const int i = blockIdx.x * 256 + threadIdx.x;
  if (i < n4) {
    const float4 f = reinterpret_cast<const float4*>(src)[i];
    dst[2 * i + 0] = __floats2half2_rn(f.x, f.y);
    dst[2 * i + 1] = __floats2half2_rn(f.z, f.w);
  }
}

template <bool HALF>
__global__ void __launch_bounds__(kElems * 64)
kgcn_kernel(const int* __restrict__ u, const int* __restrict__ v,
            const float* __restrict__ usr_emb, const float* __restrict__ item_emb,
            const float* __restrict__ ent_emb, const __half* __restrict__ ent_h,
            const float* __restrict__ rel_emb,
            const float* __restrict__ W, const float* __restrict__ bias,
            const int* __restrict__ adj_ent, const int* __restrict__ adj_rel,
            float* __restrict__ out)
{
  const int tid = threadIdx.x;
  const int wv  = tid >> 6;
  const int ln  = tid & 63;
  const int b   = blockIdx.x * kElems + wv;

  __shared__ float4 s_w4[kDim * 16];                         // 16,384 B
  __shared__ float  s_relt[kDim * 65];                       // 16,640 B
  __shared__ __align__(16) float s_pre[kElems][kVecs][kDim]; // 18,432 B

  // ---- staging loads (coalesced float4) ----
  const float4* W4 = reinterpret_cast<const float4*>(W);
  const float4* R4 = reinterpret_cast<const float4*>(rel_emb);
  const float4 wst0 = W4[tid];
  const float4 wst1 = W4[512 + tid];
  const float4 rst0 = R4[tid];
  const float4 rst1 = (512 + tid < kRelChunks) ? R4[512 + tid]
                                               : make_float4(0.f, 0.f, 0.f, 0.f);

  // ---- adjacency chain (registers + cross-lane only) ----
  const int   uid = u[b];
  const int   vid = v[b];
  const float ue  = usr_emb[(size_t)uid * kDim + ln];
  const float ev0 = item_emb[(size_t)vid * kDim + ln];
  const int   e0  = (vid >= kItemInKG) ? kNumEnt : vid;   // pad entity

  int e1v = 0, r1v = 0;
  if (ln < kNN) {
    e1v = adj_ent[(size_t)e0 * kNN + ln];
    r1v = adj_rel[(size_t)e0 * kNN + ln];
  }
  const int parent = __shfl(e1v, ln >> 3, 64);   // sources are lanes 0..7
  const int e2v    = adj_ent[(size_t)parent * kNN + (ln & 7)];
  const int r2v    = adj_rel[(size_t)parent * kNN + (ln & 7)];

  // ---- staging writes ----
  {
    // W: chunk-XOR swizzle; read back at (k4&8)|((k4^ln)&7) -> natural order.
    int id = tid, row = id >> 4, col = id & 15;
    s_w4[(row << 4) | (col & 8) | ((col ^ row) & 7)] = wst0;
    id = 512 + tid; row = id >> 4; col = id & 15;
    s_w4[(row << 4) | (col & 8) | ((col ^ row) & 7)] = wst1;
  }
  {
    // rel transposed: s_relt[k*65 + r] = rel[r][k]; banks 2-way = free.
    int id = tid, r = id >> 4, c = (id & 15) << 2;
    s_relt[(c + 0) * 65 + r] = rst0.x;
    s_relt[(c + 1) * 65 + r] = rst0.y;
    s_relt[(c + 2) * 65 + r] = rst0.z;
    s_relt[(c + 3) * 65 + r] = rst0.w;
    id = 512 + tid; r = id >> 4; c = (id & 15) << 2;  // rows 61..63: zeros
    s_relt[(c + 0) * 65 + r] = rst1.x;
    s_relt[(c + 1) * 65 + r] = rst1.y;
    s_relt[(c + 2) * 65 + r] = rst1.z;
    s_relt[(c + 3) * 65 + r] = rst1.w;
  }

  // ---- hop-1 embedding gathers (ids wave-uniform via readlane -> saddr) ----
  float ev1r[kNN];
  #pragma unroll
  for (int m = 0; m < kNN; ++m) {
    const size_t row = (size_t)__builtin_amdgcn_readlane(e1v, m) * kDim + ln;
    ev1r[m] = HALF ? __half2float(ent_h[row]) : ent_emb[row];
  }

  __syncthreads();   // staging visible

  // ---- t[r] = dot(ue, rel_emb[r]), lane = r. Column reads: 2-way = free ----
  float t;
  {
    const float* relc = &s_relt[ln];
    float a0 = 0.f, a1 = 0.f, a2 = 0.f, a3 = 0.f;
    #pragma unroll
    for (int k = 0; k < kDim; k += 4) {
      a0 = fmaf(readlane_f(ue, k + 0), relc[(k + 0) * 65], a0);
      a1 = fmaf(readlane_f(ue, k + 1), relc[(k + 1) * 65], a1);
      a2 = fmaf(readlane_f(ue, k + 2), relc[(k + 2) * 65], a2);
      a3 = fmaf(readlane_f(ue, k + 3), relc[(k + 3) * 65], a3);
    }
    t = (a0 + a1) + (a2 + a3);
  }

  // ---- softmaxes: score = bpermute lookup of t; 8-lane groups {1,2,4} ----
  float w2v;   // hop-2 weight for pair (m = ln>>3, n = ln&7)
  {
    const float s2 = __shfl(t, r2v, 64);
    float mx = s2;
    #pragma unroll
    for (int m = 1; m <= 4; m <<= 1) mx = fmaxf(mx, __shfl_xor(mx, m, 64));
    const float e = __expf(s2 - mx);
    float sm = e;
    #pragma unroll
    for (int m = 1; m <= 4; m <<= 1) sm += __shfl_xor(sm, m, 64);
    w2v = e / sm;
  }
  float w0v;   // hop-0 weight, valid on lanes 0..7 (reused for iter-1)
  {
    const float s0 = __shfl(t, r1v, 64);
    float mx = s0;
    #pragma unroll
    for (int m = 1; m <= 4; m <<= 1) mx = fmaxf(mx, __shfl_xor(mx, m, 64));
    w0v = __expf(s0 - mx);
    float sm = w0v;
    #pragma unroll
    for (int m = 1; m <= 4; m <<= 1) sm += __shfl_xor(sm, m, 64);
    w0v /= sm;
  }

  // ---- aggregation (lane = dim) ----
  {
    float agg = 0.f;
    #pragma unroll
    for (int n = 0; n < kNN; ++n)
      agg = fmaf(readlane_f(w0v, n), ev1r[n], agg);
    s_pre[wv][0][ln] = ev0 + agg;
  }
  // rows 1..8: gathers inline, unroll 2 (no prefetch arrays -- R5 lesson).
  #pragma unroll 2
  for (int m = 0; m < kNN; ++m) {
    float acc = 0.f;
    #pragma unroll
    for (int n = 0; n < kNN; ++n) {
      const size_t row =
          (size_t)__builtin_amdgcn_readlane(e2v, m * kNN + n) * kDim + ln;
      const float g = HALF ? __half2float(ent_h[row]) : ent_emb[row];
      acc = fmaf(readlane_f(w2v, m * kNN + n), g, acc);
    }
    s_pre[wv][1 + m][ln] = ev1r[m] + acc;
  }

  // ---- Wreg: ONE swizzled 16-read pass -> natural-order W[ln] row,
  // kept as v2f pairs for packed FMA ----
  v2f Wp[32];
  #pragma unroll
  for (int k4 = 0; k4 < 16; ++k4) {
    const float4 wq = s_w4[(ln << 4) | (k4 & 8) | ((k4 ^ ln) & 7)];
    Wp[2 * k4 + 0] = v2f{wq.x, wq.y};
    Wp[2 * k4 + 1] = v2f{wq.z, wq.w};
  }

  const float bln = bias[ln];

  // ---- 9 batched matvecs: p-reads are LDS b128 broadcasts; packed FMA
  // halves the issue count (v_pk_fma_f32 = the fp32 vector-peak path) ----
  float h[kVecs];
  #pragma unroll
  for (int m = 0; m < kVecs; ++m) {
    const float* p0 = &s_pre[wv][m][0];
    v2f acc01 = v2f{0.f, 0.f}, acc23 = v2f{0.f, 0.f};
    #pragma unroll
    for (int q = 0; q < 16; ++q) {
      const float4 p = *reinterpret_cast<const float4*>(p0 + (q << 2));
      pk_fma(acc01, Wp[2 * q + 0], v2f{p.x, p.y});
      pk_fma(acc23, Wp[2 * q + 1], v2f{p.z, p.w});
    }
    h[m] = fast_sigmoid((acc01.x + acc01.y) + (acc23.x + acc23.y) + bln);
  }

  // ---- iter-1 hop-0 (same ue, same rels -> reuse w0) ----
  {
    float pre = h[0];
    #pragma unroll
    for (int n = 0; n < kNN; ++n)
      pre = fmaf(readlane_f(w0v, n), h[1 + n], pre);
    s_pre[wv][0][ln] = pre;   // wave-internal DS ordering: no barrier needed
  }

  // ---- final matvec + tanh + user dot ----
  {
    const float* p0 = &s_pre[wv][0][0];
    v2f acc01 = v2f{0.f, 0.f}, acc23 = v2f{0.f, 0.f};
    #pragma unroll
    for (int q = 0; q < 16; ++q) {
      const float4 p = *reinterpret_cast<const float4*>(p0 + (q << 2));
      pk_fma(acc01, Wp[2 * q + 0], v2f{p.x, p.y});
      pk_fma(acc23, Wp[2 * q + 1], v2f{p.z, p.w});
    }
    const float item =
        fast_tanh((acc01.x + acc01.y) + (acc23.x + acc23.y) + bln);
    float tt = ue * item;
    #pragma unroll
    for (int off = 32; off > 0; off >>= 1)
      tt += __shfl_xor(tt, off, 64);
    if (ln == 0) out[b] = fast_sigmoid(tt);
  }
}

}  // namespace

extern "C" void kernel_launch(void* const* d_in, const int* in_sizes, int n_in,
                              void* d_out, int out_size, void* d_ws, size_t ws_size,
                              hipStream_t stream) {
  const int*   u        = (const int*)d_in[0];
  const int*   v        = (const int*)d_in[1];
  const float* usr_emb  = (const float*)d_in[2];
  const float* item_emb = (const float*)d_in[3];
  const float* ent_emb  = (const float*)d_in[4];
  const float* rel_emb  = (const float*)d_in[5];
  const float* W        = (const float*)d_in[6];
  const float* bias     = (const float*)d_in[7];
  const int*   adj_ent  = (const int*)d_in[8];
  const int*   adj_rel  = (const int*)d_in[9];
  float*       out      = (float*)d_out;

  const int B = in_sizes[0];   // 16384, divisible by kElems=8
  dim3 grid(B / kElems), block(kElems * 64);

  const bool use_half = (ws_size >= kEntHalfBytes);
  if (use_half) {
    __half* ent_h = (__half*)d_ws;
    const int n4 = (kNumEnt + 1) * kDim / 4;   // 1,600,016 float4 chunks
    hipLaunchKernelGGL(conv_kernel, dim3((n4 + 255) / 256), dim3(256), 0,
                       stream, ent_emb, (__half2*)ent_h, n4);
    hipLaunchKernelGGL((kgcn_kernel<true>), grid, block, 0, stream,
                       u, v, usr_emb, item_emb, ent_emb, ent_h, rel_emb, W,
                       bias, adj_ent, adj_rel, out);
  } else {
    hipLaunchKernelGGL((kgcn_kernel<false>), grid, block, 0, stream,
                       u, v, usr_emb, item_emb, ent_emb, (const __half*)d_ws,
                       rel_emb, W, bias, adj_ent, adj_rel, out);
  }
}

// Round 10
// 65.234 us; speedup vs baseline: 1.2559x; 1.0164x over previous
//
#include <hip/hip_runtime.h>
#include <hip/hip_fp16.h>

// KGCN forward, MI355X. R10 = R9 + two changes:
//  - __launch_bounds__(512,4): R9's VGPR_Count=64 proved the compiler was NOT
//    register-caching the W row (Wp[32] alone needs 64 VGPRs) -- it re-read
//    the swizzled s_w4 chunks inside every matvec (160 extra conflicted b128
//    reads/wave; conflict count frozen at 1.35M across R7-R9). The CU-shared
//    LDS pipe is the binding resource (~330 LDS ops x ~10cy x 64 waves/CU
//    ~= 70us ~= measured dur). Cap 128 VGPR -> W genuinely cached once.
//  - aggregation unroll 4 (32 gathers in flight) with the VGPR headroom.

namespace {

constexpr int kDim      = 64;
constexpr int kNN       = 8;
constexpr int kNumEnt   = 100000;
constexpr int kItemInKG = 20000;
constexpr int kElems    = 8;     // batch elements (waves) per block
constexpr int kVecs     = 9;     // pre0 + 8x pre1 rows per element
constexpr int kRelChunks = 976;  // 61 rel rows * 16 float4 chunks
constexpr size_t kEntHalfBytes = (size_t)(kNumEnt + 1) * kDim * sizeof(__half);

typedef float v2f __attribute__((ext_vector_type(2)));

__device__ __forceinline__ float fast_sigmoid(float x) {
  return 1.0f / (1.0f + __expf(-x));
}
__device__ __forceinline__ float fast_tanh(float x) {
  return 2.0f / (1.0f + __expf(-2.0f * x)) - 1.0f;
}
__device__ __forceinline__ float readlane_f(float v, int lane) {
  return __int_as_float(__builtin_amdgcn_readlane(__float_as_int(v), lane));
}
// packed fp32 FMA: acc = a*b + acc (2 elements per issue)
__device__ __forceinline__ void pk_fma(v2f& acc, v2f a, v2f b) {
  asm("v_pk_fma_f32 %0, %1, %2, %0" : "+v"(acc) : "v"(a), "v"(b));
}

// ---- pre-pass: ent_emb fp32 -> fp16 into workspace ----
__global__ void __launch_bounds__(256)
conv_kernel(const float* __restrict__ src, __half2* __restrict__ dst, int n4) {
  const int i = blockIdx.x * 256 + threadIdx.x;
  if (i < n4) {
    const float4 f = reinterpret_cast<const float4*>(src)[i];
    dst[2 * i + 0] = __floats2half2_rn(f.x, f.y);
    dst[2 * i + 1] = __floats2half2_rn(f.z, f.w);
  }
}

template <bool HALF>
__global__ void __launch_bounds__(kElems * 64, 4)
kgcn_kernel(const int* __restrict__ u, const int* __restrict__ v,
            const float* __restrict__ usr_emb, const float* __restrict__ item_emb,
            const float* __restrict__ ent_emb, const __half* __restrict__ ent_h,
            const float* __restrict__ rel_emb,
            const float* __restrict__ W, const float* __restrict__ bias,
            const int* __restrict__ adj_ent, const int* __restrict__ adj_rel,
            float* __restrict__ out)
{
  const int tid = threadIdx.x;
  const int wv  = tid >> 6;
  const int ln  = tid & 63;
  const int b   = blockIdx.x * kElems + wv;

  __shared__ float4 s_w4[kDim * 16];                         // 16,384 B
  __shared__ float  s_relt[kDim * 65];                       // 16,640 B
  __shared__ __align__(16) float s_pre[kElems][kVecs][kDim]; // 18,432 B

  // ---- staging loads (coalesced float4) ----
  const float4* W4 = reinterpret_cast<const float4*>(W);
  const float4* R4 = reinterpret_cast<const float4*>(rel_emb);
  const float4 wst0 = W4[tid];
  const float4 wst1 = W4[512 + tid];
  const float4 rst0 = R4[tid];
  const float4 rst1 = (512 + tid < kRelChunks) ? R4[512 + tid]
                                               : make_float4(0.f, 0.f, 0.f, 0.f);

  // ---- adjacency chain (registers + cross-lane only) ----
  const int   uid = u[b];
  const int   vid = v[b];
  const float ue  = usr_emb[(size_t)uid * kDim + ln];
  const float ev0 = item_emb[(size_t)vid * kDim + ln];
  const int   e0  = (vid >= kItemInKG) ? kNumEnt : vid;   // pad entity

  int e1v = 0, r1v = 0;
  if (ln < kNN) {
    e1v = adj_ent[(size_t)e0 * kNN + ln];
    r1v = adj_rel[(size_t)e0 * kNN + ln];
  }
  const int parent = __shfl(e1v, ln >> 3, 64);   // sources are lanes 0..7
  const int e2v    = adj_ent[(size_t)parent * kNN + (ln & 7)];
  const int r2v    = adj_rel[(size_t)parent * kNN + (ln & 7)];

  // ---- staging writes ----
  {
    // W: chunk-XOR swizzle; read back at (k4&8)|((k4^ln)&7) -> natural order.
    int id = tid, row = id >> 4, col = id & 15;
    s_w4[(row << 4) | (col & 8) | ((col ^ row) & 7)] = wst0;
    id = 512 + tid; row = id >> 4; col = id & 15;
    s_w4[(row << 4) | (col & 8) | ((col ^ row) & 7)] = wst1;
  }
  {
    // rel transposed: s_relt[k*65 + r] = rel[r][k]; banks 2-way = free.
    int id = tid, r = id >> 4, c = (id & 15) << 2;
    s_relt[(c + 0) * 65 + r] = rst0.x;
    s_relt[(c + 1) * 65 + r] = rst0.y;
    s_relt[(c + 2) * 65 + r] = rst0.z;
    s_relt[(c + 3) * 65 + r] = rst0.w;
    id = 512 + tid; r = id >> 4; c = (id & 15) << 2;  // rows 61..63: zeros
    s_relt[(c + 0) * 65 + r] = rst1.x;
    s_relt[(c + 1) * 65 + r] = rst1.y;
    s_relt[(c + 2) * 65 + r] = rst1.z;
    s_relt[(c + 3) * 65 + r] = rst1.w;
  }

  // ---- hop-1 embedding gathers (ids wave-uniform via readlane -> saddr) ----
  float ev1r[kNN];
  #pragma unroll
  for (int m = 0; m < kNN; ++m) {
    const size_t row = (size_t)__builtin_amdgcn_readlane(e1v, m) * kDim + ln;
    ev1r[m] = HALF ? __half2float(ent_h[row]) : ent_emb[row];
  }

  __syncthreads();   // staging visible

  // ---- t[r] = dot(ue, rel_emb[r]), lane = r. Column reads: 2-way = free ----
  float t;
  {
    const float* relc = &s_relt[ln];
    float a0 = 0.f, a1 = 0.f, a2 = 0.f, a3 = 0.f;
    #pragma unroll
    for (int k = 0; k < kDim; k += 4) {
      a0 = fmaf(readlane_f(ue, k + 0), relc[(k + 0) * 65], a0);
      a1 = fmaf(readlane_f(ue, k + 1), relc[(k + 1) * 65], a1);
      a2 = fmaf(readlane_f(ue, k + 2), relc[(k + 2) * 65], a2);
      a3 = fmaf(readlane_f(ue, k + 3), relc[(k + 3) * 65], a3);
    }
    t = (a0 + a1) + (a2 + a3);
  }

  // ---- softmaxes: score = bpermute lookup of t; 8-lane groups {1,2,4} ----
  float w2v;   // hop-2 weight for pair (m = ln>>3, n = ln&7)
  {
    const float s2 = __shfl(t, r2v, 64);
    float mx = s2;
    #pragma unroll
    for (int m = 1; m <= 4; m <<= 1) mx = fmaxf(mx, __shfl_xor(mx, m, 64));
    const float e = __expf(s2 - mx);
    float sm = e;
    #pragma unroll
    for (int m = 1; m <= 4; m <<= 1) sm += __shfl_xor(sm, m, 64);
    w2v = e / sm;
  }
  float w0v;   // hop-0 weight, valid on lanes 0..7 (reused for iter-1)
  {
    const float s0 = __shfl(t, r1v, 64);
    float mx = s0;
    #pragma unroll
    for (int m = 1; m <= 4; m <<= 1) mx = fmaxf(mx, __shfl_xor(mx, m, 64));
    w0v = __expf(s0 - mx);
    float sm = w0v;
    #pragma unroll
    for (int m = 1; m <= 4; m <<= 1) sm += __shfl_xor(sm, m, 64);
    w0v /= sm;
  }

  // ---- aggregation (lane = dim) ----
  {
    float agg = 0.f;
    #pragma unroll
    for (int n = 0; n < kNN; ++n)
      agg = fmaf(readlane_f(w0v, n), ev1r[n], agg);
    s_pre[wv][0][ln] = ev0 + agg;
  }
  // rows 1..8: gathers inline, unroll 4 (32 loads in flight; VGPR headroom
  // from launch_bounds(512,4)).
  #pragma unroll 4
  for (int m = 0; m < kNN; ++m) {
    float acc = 0.f;
    #pragma unroll
    for (int n = 0; n < kNN; ++n) {
      const size_t row =
          (size_t)__builtin_amdgcn_readlane(e2v, m * kNN + n) * kDim + ln;
      const float g = HALF ? __half2float(ent_h[row]) : ent_emb[row];
      acc = fmaf(readlane_f(w2v, m * kNN + n), g, acc);
    }
    s_pre[wv][1 + m][ln] = ev1r[m] + acc;
  }

  // ---- Wreg: ONE swizzled 16-read pass -> natural-order W[ln] row,
  // kept as v2f pairs for packed FMA (now genuinely register-resident) ----
  v2f Wp[32];
  #pragma unroll
  for (int k4 = 0; k4 < 16; ++k4) {
    const float4 wq = s_w4[(ln << 4) | (k4 & 8) | ((k4 ^ ln) & 7)];
    Wp[2 * k4 + 0] = v2f{wq.x, wq.y};
    Wp[2 * k4 + 1] = v2f{wq.z, wq.w};
  }

  const float bln = bias[ln];

  // ---- 9 batched matvecs: p-reads are LDS b128 broadcasts; packed FMA ----
  float h[kVecs];
  #pragma unroll
  for (int m = 0; m < kVecs; ++m) {
    const float* p0 = &s_pre[wv][m][0];
    v2f acc01 = v2f{0.f, 0.f}, acc23 = v2f{0.f, 0.f};
    #pragma unroll
    for (int q = 0; q < 16; ++q) {
      const float4 p = *reinterpret_cast<const float4*>(p0 + (q << 2));
      pk_fma(acc01, Wp[2 * q + 0], v2f{p.x, p.y});
      pk_fma(acc23, Wp[2 * q + 1], v2f{p.z, p.w});
    }
    h[m] = fast_sigmoid((acc01.x + acc01.y) + (acc23.x + acc23.y) + bln);
  }

  // ---- iter-1 hop-0 (same ue, same rels -> reuse w0) ----
  {
    float pre = h[0];
    #pragma unroll
    for (int n = 0; n < kNN; ++n)
      pre = fmaf(readlane_f(w0v, n), h[1 + n], pre);
    s_pre[wv][0][ln] = pre;   // wave-internal DS ordering: no barrier needed
  }

  // ---- final matvec + tanh + user dot ----
  {
    const float* p0 = &s_pre[wv][0][0];
    v2f acc01 = v2f{0.f, 0.f}, acc23 = v2f{0.f, 0.f};
    #pragma unroll
    for (int q = 0; q < 16; ++q) {
      const float4 p = *reinterpret_cast<const float4*>(p0 + (q << 2));
      pk_fma(acc01, Wp[2 * q + 0], v2f{p.x, p.y});
      pk_fma(acc23, Wp[2 * q + 1], v2f{p.z, p.w});
    }
    const float item =
        fast_tanh((acc01.x + acc01.y) + (acc23.x + acc23.y) + bln);
    float tt = ue * item;
    #pragma unroll
    for (int off = 32; off > 0; off >>= 1)
      tt += __shfl_xor(tt, off, 64);
    if (ln == 0) out[b] = fast_sigmoid(tt);
  }
}

}  // namespace

extern "C" void kernel_launch(void* const* d_in, const int* in_sizes, int n_in,
                              void* d_out, int out_size, void* d_ws, size_t ws_size,
                              hipStream_t stream) {
  const int*   u        = (const int*)d_in[0];
  const int*   v        = (const int*)d_in[1];
  const float* usr_emb  = (const float*)d_in[2];
  const float* item_emb = (const float*)d_in[3];
  const float* ent_emb  = (const float*)d_in[4];
  const float* rel_emb  = (const float*)d_in[5];
  const float* W        = (const float*)d_in[6];
  const float* bias     = (const float*)d_in[7];
  const int*   adj_ent  = (const int*)d_in[8];
  const int*   adj_rel  = (const int*)d_in[9];
  float*       out      = (float*)d_out;

  const int B = in_sizes[0];   // 16384, divisible by kElems=8
  dim3 grid(B / kElems), block(kElems * 64);

  const bool use_half = (ws_size >= kEntHalfBytes);
  if (use_half) {
    __half* ent_h = (__half*)d_ws;
    const int n4 = (kNumEnt + 1) * kDim / 4;
    hipLaunchKernelGGL(conv_kernel, dim3((n4 + 255) / 256), dim3(256), 0,
                       stream, ent_emb, (__half2*)ent_h, n4);
    hipLaunchKernelGGL((kgcn_kernel<true>), grid, block, 0, stream,
                       u, v, usr_emb, item_emb, ent_emb, ent_h, rel_emb, W,
                       bias, adj_ent, adj_rel, out);
  } else {
    hipLaunchKernelGGL((kgcn_kernel<false>), grid, block, 0, stream,
                       u, v, usr_emb, item_emb, ent_emb, (const __half*)d_ws,
                       rel_emb, W, bias, adj_ent, adj_rel, out);
  }
}

// Round 11
// 59.260 us; speedup vs baseline: 1.3825x; 1.1008x over previous
//
#include <hip/hip_runtime.h>
#include <hip/hip_fp16.h>

// KGCN forward, MI355X. R11 = R9 + deep gather prefetch + real register caching.
// Evidence: R9 vs R4 showed halving gather bytes bought ~nothing -> kernel is
// gather-LATENCY bound, not BW bound (waves ~90% stalled at 11 waves/CU).
// R10 showed __launch_bounds__ min-waves can't lower the allocator's occupancy
// target (VGPR stuck at 64, W never cached). Fixes:
//  - amdgpu_waves_per_eu(4,4): allocator targets 128 VGPRs.
//  - ALL 64 hop-2 fp16 gathers issued right after e2v resolves (1 VGPR each),
//    ~600 cy of t-pass+softmax in flight; asm pins AFTER softmax stop the
//    compiler sinking the loads (pins at the loads would force early vmcnt0).
//  - Wp[32] pinned via asm -> W read from LDS exactly once per wave.

namespace {

constexpr int kDim      = 64;
constexpr int kNN       = 8;
constexpr int kNumEnt   = 100000;
constexpr int kItemInKG = 20000;
constexpr int kElems    = 8;     // batch elements (waves) per block
constexpr int kVecs     = 9;     // pre0 + 8x pre1 rows per element
constexpr int kRelChunks = 976;  // 61 rel rows * 16 float4 chunks
constexpr size_t kEntHalfBytes = (size_t)(kNumEnt + 1) * kDim * sizeof(__half);

typedef float v2f __attribute__((ext_vector_type(2)));

__device__ __forceinline__ float fast_sigmoid(float x) {
  return 1.0f / (1.0f + __expf(-x));
}
__device__ __forceinline__ float fast_tanh(float x) {
  return 2.0f / (1.0f + __expf(-2.0f * x)) - 1.0f;
}
__device__ __forceinline__ float readlane_f(float v, int lane) {
  return __int_as_float(__builtin_amdgcn_readlane(__float_as_int(v), lane));
}
// packed fp32 FMA: acc = a*b + acc (2 elements per issue)
__device__ __forceinline__ void pk_fma(v2f& acc, v2f a, v2f b) {
  asm("v_pk_fma_f32 %0, %1, %2, %0" : "+v"(acc) : "v"(a), "v"(b));
}

// ---- pre-pass: ent_emb fp32 -> fp16 into workspace ----
__global__ void __launch_bounds__(256)
conv_kernel(const float* __restrict__ src, __half2* __restrict__ dst, int n4) {
  const int i = blockIdx.x * 256 + threadIdx.x;
  if (i < n4) {
    const float4 f = reinterpret_cast<const float4*>(src)[i];
    dst[2 * i + 0] = __floats2half2_rn(f.x, f.y);
    dst[2 * i + 1] = __floats2half2_rn(f.z, f.w);
  }
}

template <bool HALF>
__global__ void __launch_bounds__(kElems * 64)
__attribute__((amdgpu_waves_per_eu(4, 4)))
kgcn_kernel(const int* __restrict__ u, const int* __restrict__ v,
            const float* __restrict__ usr_emb, const float* __restrict__ item_emb,
            const float* __restrict__ ent_emb, const __half* __restrict__ ent_h,
            const float* __restrict__ rel_emb,
            const float* __restrict__ W, const float* __restrict__ bias,
            const int* __restrict__ adj_ent, const int* __restrict__ adj_rel,
            float* __restrict__ out)
{
  const int tid = threadIdx.x;
  const int wv  = tid >> 6;
  const int ln  = tid & 63;
  const int b   = blockIdx.x * kElems + wv;

  __shared__ float4 s_w4[kDim * 16];                         // 16,384 B
  __shared__ float  s_relt[kDim * 65];                       // 16,640 B
  __shared__ __align__(16) float s_pre[kElems][kVecs][kDim]; // 18,432 B

  // ---- staging loads (coalesced float4) ----
  const float4* W4 = reinterpret_cast<const float4*>(W);
  const float4* R4 = reinterpret_cast<const float4*>(rel_emb);
  const float4 wst0 = W4[tid];
  const float4 wst1 = W4[512 + tid];
  const float4 rst0 = R4[tid];
  const float4 rst1 = (512 + tid < kRelChunks) ? R4[512 + tid]
                                               : make_float4(0.f, 0.f, 0.f, 0.f);

  // ---- adjacency chain (registers + cross-lane only) ----
  const int   uid = u[b];
  const int   vid = v[b];
  const float ue  = usr_emb[(size_t)uid * kDim + ln];
  const float ev0 = item_emb[(size_t)vid * kDim + ln];
  const int   e0  = (vid >= kItemInKG) ? kNumEnt : vid;   // pad entity

  int e1v = 0, r1v = 0;
  if (ln < kNN) {
    e1v = adj_ent[(size_t)e0 * kNN + ln];
    r1v = adj_rel[(size_t)e0 * kNN + ln];
  }
  const int parent = __shfl(e1v, ln >> 3, 64);   // sources are lanes 0..7
  const int e2v    = adj_ent[(size_t)parent * kNN + (ln & 7)];
  const int r2v    = adj_rel[(size_t)parent * kNN + (ln & 7)];

  // ---- staging writes ----
  {
    // W: chunk-XOR swizzle; read back at (k4&8)|((k4^ln)&7) -> natural order.
    int id = tid, row = id >> 4, col = id & 15;
    s_w4[(row << 4) | (col & 8) | ((col ^ row) & 7)] = wst0;
    id = 512 + tid; row = id >> 4; col = id & 15;
    s_w4[(row << 4) | (col & 8) | ((col ^ row) & 7)] = wst1;
  }
  {
    // rel transposed: s_relt[k*65 + r] = rel[r][k]; banks 2-way = free.
    int id = tid, r = id >> 4, c = (id & 15) << 2;
    s_relt[(c + 0) * 65 + r] = rst0.x;
    s_relt[(c + 1) * 65 + r] = rst0.y;
    s_relt[(c + 2) * 65 + r] = rst0.z;
    s_relt[(c + 3) * 65 + r] = rst0.w;
    id = 512 + tid; r = id >> 4; c = (id & 15) << 2;  // rows 61..63: zeros
    s_relt[(c + 0) * 65 + r] = rst1.x;
    s_relt[(c + 1) * 65 + r] = rst1.y;
    s_relt[(c + 2) * 65 + r] = rst1.z;
    s_relt[(c + 3) * 65 + r] = rst1.w;
  }

  // ---- hop-1 embedding gathers (ids wave-uniform via readlane -> saddr) ----
  float ev1r[kNN];
  #pragma unroll
  for (int m = 0; m < kNN; ++m) {
    const size_t row = (size_t)__builtin_amdgcn_readlane(e1v, m) * kDim + ln;
    ev1r[m] = HALF ? __half2float(ent_h[row]) : ent_emb[row];
  }

  // ---- issue ALL 64 hop-2 gathers now (fp16 -> 1 VGPR each). They stay in
  // flight across the barrier + t-pass + softmax (~600 cy of cover).
  unsigned int g16[kDim];
  if constexpr (HALF) {
    const unsigned short* eh = reinterpret_cast<const unsigned short*>(ent_h);
    #pragma unroll
    for (int i = 0; i < kDim; ++i) {
      const size_t row = (size_t)__builtin_amdgcn_readlane(e2v, i) * kDim + ln;
      g16[i] = eh[row];
    }
  }

  __syncthreads();   // staging visible

  // ---- t[r] = dot(ue, rel_emb[r]), lane = r. Column reads: 2-way = free ----
  float t;
  {
    const float* relc = &s_relt[ln];
    float a0 = 0.f, a1 = 0.f, a2 = 0.f, a3 = 0.f;
    #pragma unroll
    for (int k = 0; k < kDim; k += 4) {
      a0 = fmaf(readlane_f(ue, k + 0), relc[(k + 0) * 65], a0);
      a1 = fmaf(readlane_f(ue, k + 1), relc[(k + 1) * 65], a1);
      a2 = fmaf(readlane_f(ue, k + 2), relc[(k + 2) * 65], a2);
      a3 = fmaf(readlane_f(ue, k + 3), relc[(k + 3) * 65], a3);
    }
    t = (a0 + a1) + (a2 + a3);
  }

  // ---- softmaxes: score = bpermute lookup of t; 8-lane groups {1,2,4} ----
  float w2v;   // hop-2 weight for pair (m = ln>>3, n = ln&7)
  {
    const float s2 = __shfl(t, r2v, 64);
    float mx = s2;
    #pragma unroll
    for (int m = 1; m <= 4; m <<= 1) mx = fmaxf(mx, __shfl_xor(mx, m, 64));
    const float e = __expf(s2 - mx);
    float sm = e;
    #pragma unroll
    for (int m = 1; m <= 4; m <<= 1) sm += __shfl_xor(sm, m, 64);
    w2v = e / sm;
  }
  float w0v;   // hop-0 weight, valid on lanes 0..7 (reused for iter-1)
  {
    const float s0 = __shfl(t, r1v, 64);
    float mx = s0;
    #pragma unroll
    for (int m = 1; m <= 4; m <<= 1) mx = fmaxf(mx, __shfl_xor(mx, m, 64));
    w0v = __expf(s0 - mx);
    float sm = w0v;
    #pragma unroll
    for (int m = 1; m <= 4; m <<= 1) sm += __shfl_xor(sm, m, 64);
    w0v /= sm;
  }

  // ---- pin the prefetched gathers HERE (a pin is a "use": placing it after
  // the softmax keeps the loads issued early but un-sinkable past this point).
  if constexpr (HALF) {
    #pragma unroll
    for (int i = 0; i < kDim; ++i) asm volatile("" : "+v"(g16[i]));
  }

  // ---- aggregation (lane = dim) ----
  {
    float agg = 0.f;
    #pragma unroll
    for (int n = 0; n < kNN; ++n)
      agg = fmaf(readlane_f(w0v, n), ev1r[n], agg);
    s_pre[wv][0][ln] = ev0 + agg;
  }
  if constexpr (HALF) {
    #pragma unroll
    for (int m = 0; m < kNN; ++m) {
      float acc = 0.f;
      #pragma unroll
      for (int n = 0; n < kNN; ++n) {
        const float g = __half2float(
            __ushort_as_half((unsigned short)g16[m * kNN + n]));
        acc = fmaf(readlane_f(w2v, m * kNN + n), g, acc);
      }
      s_pre[wv][1 + m][ln] = ev1r[m] + acc;
    }
  } else {
    #pragma unroll 2
    for (int m = 0; m < kNN; ++m) {
      float acc = 0.f;
      #pragma unroll
      for (int n = 0; n < kNN; ++n) {
        const size_t row =
            (size_t)__builtin_amdgcn_readlane(e2v, m * kNN + n) * kDim + ln;
        acc = fmaf(readlane_f(w2v, m * kNN + n), ent_emb[row], acc);
      }
      s_pre[wv][1 + m][ln] = ev1r[m] + acc;
    }
  }

  // ---- Wreg: ONE swizzled 16-read pass -> natural-order W[ln] row; pinned
  // so the compiler cannot rematerialize the LDS reads per matvec.
  v2f Wp[32];
  #pragma unroll
  for (int k4 = 0; k4 < 16; ++k4) {
    const float4 wq = s_w4[(ln << 4) | (k4 & 8) | ((k4 ^ ln) & 7)];
    Wp[2 * k4 + 0] = v2f{wq.x, wq.y};
    Wp[2 * k4 + 1] = v2f{wq.z, wq.w};
  }
  #pragma unroll
  for (int i = 0; i < 32; ++i) asm volatile("" : "+v"(Wp[i]));

  const float bln = bias[ln];

  // ---- 9 batched matvecs: p-reads are LDS b128 broadcasts; packed FMA ----
  float h[kVecs];
  #pragma unroll
  for (int m = 0; m < kVecs; ++m) {
    const float* p0 = &s_pre[wv][m][0];
    v2f acc01 = v2f{0.f, 0.f}, acc23 = v2f{0.f, 0.f};
    #pragma unroll
    for (int q = 0; q < 16; ++q) {
      const float4 p = *reinterpret_cast<const float4*>(p0 + (q << 2));
      pk_fma(acc01, Wp[2 * q + 0], v2f{p.x, p.y});
      pk_fma(acc23, Wp[2 * q + 1], v2f{p.z, p.w});
    }
    h[m] = fast_sigmoid((acc01.x + acc01.y) + (acc23.x + acc23.y) + bln);
  }

  // ---- iter-1 hop-0 (same ue, same rels -> reuse w0) ----
  {
    float pre = h[0];
    #pragma unroll
    for (int n = 0; n < kNN; ++n)
      pre = fmaf(readlane_f(w0v, n), h[1 + n], pre);
    s_pre[wv][0][ln] = pre;   // wave-internal DS ordering: no barrier needed
  }

  // ---- final matvec + tanh + user dot ----
  {
    const float* p0 = &s_pre[wv][0][0];
    v2f acc01 = v2f{0.f, 0.f}, acc23 = v2f{0.f, 0.f};
    #pragma unroll
    for (int q = 0; q < 16; ++q) {
      const float4 p = *reinterpret_cast<const float4*>(p0 + (q << 2));
      pk_fma(acc01, Wp[2 * q + 0], v2f{p.x, p.y});
      pk_fma(acc23, Wp[2 * q + 1], v2f{p.z, p.w});
    }
    const float item =
        fast_tanh((acc01.x + acc01.y) + (acc23.x + acc23.y) + bln);
    float tt = ue * item;
    #pragma unroll
    for (int off = 32; off > 0; off >>= 1)
      tt += __shfl_xor(tt, off, 64);
    if (ln == 0) out[b] = fast_sigmoid(tt);
  }
}

}  // namespace

extern "C" void kernel_launch(void* const* d_in, const int* in_sizes, int n_in,
                              void* d_out, int out_size, void* d_ws, size_t ws_size,
                              hipStream_t stream) {
  const int*   u        = (const int*)d_in[0];
  const int*   v        = (const int*)d_in[1];
  const float* usr_emb  = (const float*)d_in[2];
  const float* item_emb = (const float*)d_in[3];
  const float* ent_emb  = (const float*)d_in[4];
  const float* rel_emb  = (const float*)d_in[5];
  const float* W        = (const float*)d_in[6];
  const float* bias     = (const float*)d_in[7];
  const int*   adj_ent  = (const int*)d_in[8];
  const int*   adj_rel  = (const int*)d_in[9];
  float*       out      = (float*)d_out;

  const int B = in_sizes[0];   // 16384, divisible by kElems=8
  dim3 grid(B / kElems), block(kElems * 64);

  const bool use_half = (ws_size >= kEntHalfBytes);
  if (use_half) {
    __half* ent_h = (__half*)d_ws;
    const int n4 = (kNumEnt + 1) * kDim / 4;
    hipLaunchKernelGGL(conv_kernel, dim3((n4 + 255) / 256), dim3(256), 0,
                       stream, ent_emb, (__half2*)ent_h, n4);
    hipLaunchKernelGGL((kgcn_kernel<true>), grid, block, 0, stream,
                       u, v, usr_emb, item_emb, ent_emb, ent_h, rel_emb, W,
                       bias, adj_ent, adj_rel, out);
  } else {
    hipLaunchKernelGGL((kgcn_kernel<false>), grid, block, 0, stream,
                       u, v, usr_emb, item_emb, ent_emb, (const __half*)d_ws,
                       rel_emb, W, bias, adj_ent, adj_rel, out);
  }
}

// Round 12
// 53.377 us; speedup vs baseline: 1.5349x; 1.1102x over previous
//
#include <hip/hip_runtime.h>
#include <hip/hip_fp16.h>

// KGCN forward, MI355X. R12: delete the VALU/LDS matvec storm, use MFMA.
// Evidence: R11 pipe accounting -- ~350 LDS instr/wave x ~6cy x 64 waves/CU
// ~= 56us ~= dur; both LDS and VALU pipes near capacity (R8: moving work
// between them hurt). MFMA 16x16x32_f16: each wave's 9 pre-rows = one 16x16
// M-tile; 8 MFMA replace 352 pk_fma + ~300 b128 LDS reads. W cached as 8
// B-fragments (32 VGPR) read once. A/B k-mappings identical -> k-permutation
// errors cancel in the contraction; n=lane&15 / C/D layouts are HW-verified.

namespace {

constexpr int kDim      = 64;
constexpr int kNN       = 8;
constexpr int kNumEnt   = 100000;
constexpr int kItemInKG = 20000;
constexpr int kElems    = 8;     // batch elements (waves) per block
constexpr int kRelChunks = 976;  // 61 rel rows * 16 float4 chunks
constexpr int kP        = 72;    // fp16 row stride (144B): conflict-free frags
constexpr size_t kEntHalfBytes = (size_t)(kNumEnt + 1) * kDim * sizeof(__half);

typedef _Float16 f16x4 __attribute__((ext_vector_type(4)));
typedef _Float16 f16x8 __attribute__((ext_vector_type(8)));
typedef float    f32x4 __attribute__((ext_vector_type(4)));

__device__ __forceinline__ float fast_sigmoid(float x) {
  return 1.0f / (1.0f + __expf(-x));
}
__device__ __forceinline__ float fast_tanh(float x) {
  return 2.0f / (1.0f + __expf(-2.0f * x)) - 1.0f;
}
__device__ __forceinline__ float readlane_f(float v, int lane) {
  return __int_as_float(__builtin_amdgcn_readlane(__float_as_int(v), lane));
}
__device__ __forceinline__ f16x8 join8(f16x4 lo, f16x4 hi) {
  return __builtin_shufflevector(lo, hi, 0, 1, 2, 3, 4, 5, 6, 7);
}

// ---- pre-pass: ent_emb fp32 -> fp16 into workspace ----
__global__ void __launch_bounds__(256)
conv_kernel(const float* __restrict__ src, __half2* __restrict__ dst, int n4) {
  const int i = blockIdx.x * 256 + threadIdx.x;
  if (i < n4) {
    const float4 f = reinterpret_cast<const float4*>(src)[i];
    dst[2 * i + 0] = __floats2half2_rn(f.x, f.y);
    dst[2 * i + 1] = __floats2half2_rn(f.z, f.w);
  }
}

template <bool HALF>
__global__ void __launch_bounds__(kElems * 64)
__attribute__((amdgpu_waves_per_eu(4, 4)))
kgcn_kernel(const int* __restrict__ u, const int* __restrict__ v,
            const float* __restrict__ usr_emb, const float* __restrict__ item_emb,
            const float* __restrict__ ent_emb, const __half* __restrict__ ent_h,
            const float* __restrict__ rel_emb,
            const float* __restrict__ W, const float* __restrict__ bias,
            const int* __restrict__ adj_ent, const int* __restrict__ adj_rel,
            float* __restrict__ out)
{
  const int tid = threadIdx.x;
  const int wv  = tid >> 6;
  const int ln  = tid & 63;
  const int lq  = ln & 15;    // quarter-lane: MFMA m/n index
  const int lg  = ln >> 4;    // lane group:   MFMA k-slot base
  const int b   = blockIdx.x * kElems + wv;

  __shared__ _Float16 s_wh[kDim * kP];     //  9,216 B  W fp16, row-major pad-72
  __shared__ float    s_relt[kDim * 65];   // 16,640 B  rel^T
  __shared__ _Float16 s_pre[80 * kP];      // 11,520 B  rows wv*9+vec (pad-read to 78)
  __shared__ _Float16 s_h[72 * kP];        // 10,368 B  hop-1 activations
  __shared__ float    s_ue[kElems][kDim];  //  2,048 B

  // ---- staging loads (coalesced float4) ----
  const float4* W4 = reinterpret_cast<const float4*>(W);
  const float4* R4 = reinterpret_cast<const float4*>(rel_emb);
  const float4 wst0 = W4[tid];
  const float4 wst1 = W4[512 + tid];
  const float4 rst0 = R4[tid];
  const float4 rst1 = (512 + tid < kRelChunks) ? R4[512 + tid]
                                               : make_float4(0.f, 0.f, 0.f, 0.f);

  // ---- adjacency chain (registers + cross-lane only) ----
  const int   uid = u[b];
  const int   vid = v[b];
  const float ue  = usr_emb[(size_t)uid * kDim + ln];
  const float ev0 = item_emb[(size_t)vid * kDim + ln];
  const int   e0  = (vid >= kItemInKG) ? kNumEnt : vid;   // pad entity

  int e1v = 0, r1v = 0;
  if (ln < kNN) {
    e1v = adj_ent[(size_t)e0 * kNN + ln];
    r1v = adj_rel[(size_t)e0 * kNN + ln];
  }
  const int parent = __shfl(e1v, ln >> 3, 64);   // sources are lanes 0..7
  const int e2v    = adj_ent[(size_t)parent * kNN + (ln & 7)];
  const int r2v    = adj_rel[(size_t)parent * kNN + (ln & 7)];

  // ---- staging writes ----
  {
    // W -> fp16 (RN scalar cvts), rows padded to 72 halfs.
    int id = tid, row = id >> 4, c4 = (id & 15) << 2;
    f16x4 h4;
    h4[0] = (_Float16)wst0.x; h4[1] = (_Float16)wst0.y;
    h4[2] = (_Float16)wst0.z; h4[3] = (_Float16)wst0.w;
    *reinterpret_cast<f16x4*>(&s_wh[row * kP + c4]) = h4;
    id = 512 + tid; row = id >> 4; c4 = (id & 15) << 2;
    f16x4 h5;
    h5[0] = (_Float16)wst1.x; h5[1] = (_Float16)wst1.y;
    h5[2] = (_Float16)wst1.z; h5[3] = (_Float16)wst1.w;
    *reinterpret_cast<f16x4*>(&s_wh[row * kP + c4]) = h5;
  }
  {
    // rel transposed: s_relt[k*65 + r] = rel[r][k]; banks 2-way = free.
    int id = tid, r = id >> 4, c = (id & 15) << 2;
    s_relt[(c + 0) * 65 + r] = rst0.x;
    s_relt[(c + 1) * 65 + r] = rst0.y;
    s_relt[(c + 2) * 65 + r] = rst0.z;
    s_relt[(c + 3) * 65 + r] = rst0.w;
    id = 512 + tid; r = id >> 4; c = (id & 15) << 2;  // rows 61..63: zeros
    s_relt[(c + 0) * 65 + r] = rst1.x;
    s_relt[(c + 1) * 65 + r] = rst1.y;
    s_relt[(c + 2) * 65 + r] = rst1.z;
    s_relt[(c + 3) * 65 + r] = rst1.w;
  }
  s_ue[wv][ln] = ue;

  // ---- hop-1 embedding gathers (ids wave-uniform via readlane -> saddr) ----
  float ev1r[kNN];
  #pragma unroll
  for (int m = 0; m < kNN; ++m) {
    const size_t row = (size_t)__builtin_amdgcn_readlane(e1v, m) * kDim + ln;
    ev1r[m] = HALF ? __half2float(ent_h[row]) : ent_emb[row];
  }

  // ---- issue ALL 64 hop-2 fp16 gathers now (in flight across barrier +
  // t-pass + softmax; pins after softmax keep them un-sinkable). R11 win.
  unsigned int g16[kDim];
  if constexpr (HALF) {
    const unsigned short* eh = reinterpret_cast<const unsigned short*>(ent_h);
    #pragma unroll
    for (int i = 0; i < kDim; ++i) {
      const size_t row = (size_t)__builtin_amdgcn_readlane(e2v, i) * kDim + ln;
      g16[i] = eh[row];
    }
  }

  __syncthreads();   // staging visible

  // ---- t[r] = dot(ue, rel_emb[r]), lane = r ----
  float t;
  {
    const float* relc = &s_relt[ln];
    float a0 = 0.f, a1 = 0.f, a2 = 0.f, a3 = 0.f;
    #pragma unroll
    for (int k = 0; k < kDim; k += 4) {
      a0 = fmaf(readlane_f(ue, k + 0), relc[(k + 0) * 65], a0);
      a1 = fmaf(readlane_f(ue, k + 1), relc[(k + 1) * 65], a1);
      a2 = fmaf(readlane_f(ue, k + 2), relc[(k + 2) * 65], a2);
      a3 = fmaf(readlane_f(ue, k + 3), relc[(k + 3) * 65], a3);
    }
    t = (a0 + a1) + (a2 + a3);
  }

  // ---- softmaxes: score = bpermute lookup of t; 8-lane groups {1,2,4} ----
  float w2v;
  {
    const float s2 = __shfl(t, r2v, 64);
    float mx = s2;
    #pragma unroll
    for (int m = 1; m <= 4; m <<= 1) mx = fmaxf(mx, __shfl_xor(mx, m, 64));
    const float e = __expf(s2 - mx);
    float sm = e;
    #pragma unroll
    for (int m = 1; m <= 4; m <<= 1) sm += __shfl_xor(sm, m, 64);
    w2v = e / sm;
  }
  float w0v;   // lanes 0..7; reused for iter-1
  {
    const float s0 = __shfl(t, r1v, 64);
    float mx = s0;
    #pragma unroll
    for (int m = 1; m <= 4; m <<= 1) mx = fmaxf(mx, __shfl_xor(mx, m, 64));
    w0v = __expf(s0 - mx);
    float sm = w0v;
    #pragma unroll
    for (int m = 1; m <= 4; m <<= 1) sm += __shfl_xor(sm, m, 64);
    w0v /= sm;
  }

  if constexpr (HALF) {
    #pragma unroll
    for (int i = 0; i < kDim; ++i) asm volatile("" : "+v"(g16[i]));
  }

  // ---- aggregation (lane = dim) -> fp16 pre-rows in LDS ----
  {
    float agg = 0.f;
    #pragma unroll
    for (int n = 0; n < kNN; ++n)
      agg = fmaf(readlane_f(w0v, n), ev1r[n], agg);
    s_pre[(wv * 9 + 0) * kP + ln] = (_Float16)(ev0 + agg);
  }
  if constexpr (HALF) {
    #pragma unroll
    for (int m = 0; m < kNN; ++m) {
      float acc = 0.f;
      #pragma unroll
      for (int n = 0; n < kNN; ++n) {
        const float g = __half2float(
            __ushort_as_half((unsigned short)g16[m * kNN + n]));
        acc = fmaf(readlane_f(w2v, m * kNN + n), g, acc);
      }
      s_pre[(wv * 9 + 1 + m) * kP + ln] = (_Float16)(ev1r[m] + acc);
    }
  } else {
    #pragma unroll 2
    for (int m = 0; m < kNN; ++m) {
      float acc = 0.f;
      #pragma unroll
      for (int n = 0; n < kNN; ++n) {
        const size_t row =
            (size_t)__builtin_amdgcn_readlane(e2v, m * kNN + n) * kDim + ln;
        acc = fmaf(readlane_f(w2v, m * kNN + n), ent_emb[row], acc);
      }
      s_pre[(wv * 9 + 1 + m) * kP + ln] = (_Float16)(ev1r[m] + acc);
    }
  }

  // ---- bias cols for this lane's D columns ----
  float bcol[4];
  #pragma unroll
  for (int tt = 0; tt < 4; ++tt) bcol[tt] = bias[tt * 16 + lq];

  // ---- B fragments: W^T, cached once (32 VGPR, 16 ds_read_b64).
  // B[k][n]: n = lq = W row (within ntile), k-slots = s*32 + lg*4 (+16).
  f16x8 Bf[8];
  #pragma unroll
  for (int tt = 0; tt < 4; ++tt) {
    #pragma unroll
    for (int s = 0; s < 2; ++s) {
      const _Float16* p = &s_wh[(tt * 16 + lq) * kP + s * 32 + lg * 4];
      Bf[tt * 2 + s] = join8(*reinterpret_cast<const f16x4*>(p),
                             *reinterpret_cast<const f16x4*>(p + 16));
    }
  }

  // ---- A fragments (own element's 9 pre-rows; m = lq) + main GEMM ----
  // Same-wave DS ordering: the rows were written by this wave.
  f16x8 Af[2];
  #pragma unroll
  for (int s = 0; s < 2; ++s) {
    const _Float16* p = &s_pre[(wv * 9 + lq) * kP + s * 32 + lg * 4];
    Af[s] = join8(*reinterpret_cast<const f16x4*>(p),
                  *reinterpret_cast<const f16x4*>(p + 16));
  }
  f32x4 acc[4];
  #pragma unroll
  for (int tt = 0; tt < 4; ++tt) acc[tt] = f32x4{0.f, 0.f, 0.f, 0.f};
  #pragma unroll
  for (int tt = 0; tt < 4; ++tt)
    #pragma unroll
    for (int s = 0; s < 2; ++s)
      acc[tt] = __builtin_amdgcn_mfma_f32_16x16x32_f16(Af[s], Bf[tt * 2 + s],
                                                       acc[tt], 0, 0, 0);

  // ---- h = sigmoid(acc + b): D row=(lg*4+r)=vec, col=t*16+lq ----
  #pragma unroll
  for (int tt = 0; tt < 4; ++tt) {
    #pragma unroll
    for (int r = 0; r < 4; ++r) {
      const int vec = lg * 4 + r;
      if (vec < 9)
        s_h[(wv * 9 + vec) * kP + tt * 16 + lq] =
            (_Float16)fast_sigmoid(acc[tt][r] + bcol[tt]);
    }
  }

  // ---- iter-1 hop-0 (reuse w0), lane = dim; overwrite pre-row 0 ----
  {
    float pre = (float)s_h[(wv * 9 + 0) * kP + ln];
    #pragma unroll
    for (int n = 0; n < kNN; ++n)
      pre = fmaf(readlane_f(w0v, n), (float)s_h[(wv * 9 + 1 + n) * kP + ln],
                 pre);
    s_pre[(wv * 9 + 0) * kP + ln] = (_Float16)pre;
  }

  // ---- final matvec via MFMA: A row 0 broadcast to all m (harmless) ----
  f16x8 Ff[2];
  #pragma unroll
  for (int s = 0; s < 2; ++s) {
    const _Float16* p = &s_pre[(wv * 9 + 0) * kP + s * 32 + lg * 4];
    Ff[s] = join8(*reinterpret_cast<const f16x4*>(p),
                  *reinterpret_cast<const f16x4*>(p + 16));
  }
  f32x4 fa[4];
  #pragma unroll
  for (int tt = 0; tt < 4; ++tt) fa[tt] = f32x4{0.f, 0.f, 0.f, 0.f};
  #pragma unroll
  for (int tt = 0; tt < 4; ++tt)
    #pragma unroll
    for (int s = 0; s < 2; ++s)
      fa[tt] = __builtin_amdgcn_mfma_f32_16x16x32_f16(Ff[s], Bf[tt * 2 + s],
                                                      fa[tt], 0, 0, 0);

  // lanes 0..15 hold D row 0 (reg 0): item[col=t*16+ln]; dot with ue.
  float part = 0.f;
  if (ln < 16) {
    #pragma unroll
    for (int tt = 0; tt < 4; ++tt) {
      const float item = fast_tanh(fa[tt][0] + bcol[tt]);
      part = fmaf(item, s_ue[wv][tt * 16 + ln], part);
    }
  }
  #pragma unroll
  for (int off = 1; off <= 8; off <<= 1)
    part += __shfl_xor(part, off, 64);
  if (ln == 0) out[b] = fast_sigmoid(part);
}

}  // namespace

extern "C" void kernel_launch(void* const* d_in, const int* in_sizes, int n_in,
                              void* d_out, int out_size, void* d_ws, size_t ws_size,
                              hipStream_t stream) {
  const int*   u        = (const int*)d_in[0];
  const int*   v        = (const int*)d_in[1];
  const float* usr_emb  = (const float*)d_in[2];
  const float* item_emb = (const float*)d_in[3];
  const float* ent_emb  = (const float*)d_in[4];
  const float* rel_emb  = (const float*)d_in[5];
  const float* W        = (const float*)d_in[6];
  const float* bias     = (const float*)d_in[7];
  const int*   adj_ent  = (const int*)d_in[8];
  const int*   adj_rel  = (const int*)d_in[9];
  float*       out      = (float*)d_out;

  const int B = in_sizes[0];   // 16384, divisible by kElems=8
  dim3 grid(B / kElems), block(kElems * 64);

  const bool use_half = (ws_size >= kEntHalfBytes);
  if (use_half) {
    __half* ent_h = (__half*)d_ws;
    const int n4 = (kNumEnt + 1) * kDim / 4;
    hipLaunchKernelGGL(conv_kernel, dim3((n4 + 255) / 256), dim3(256), 0,
                       stream, ent_emb, (__half2*)ent_h, n4);
    hipLaunchKernelGGL((kgcn_kernel<true>), grid, block, 0, stream,
                       u, v, usr_emb, item_emb, ent_emb, ent_h, rel_emb, W,
                       bias, adj_ent, adj_rel, out);
  } else {
    hipLaunchKernelGGL((kgcn_kernel<false>), grid, block, 0, stream,
                       u, v, usr_emb, item_emb, ent_emb, (const __half*)d_ws,
                       rel_emb, W, bias, adj_ent, adj_rel, out);
  }
}

// Round 14
// 52.377 us; speedup vs baseline: 1.5642x; 1.0191x over previous
//
#include <hip/hip_runtime.h>
#include <hip/hip_fp16.h>

// KGCN forward, MI355X. R14 = R13 with the epilogue bug fixed.
// R13 failure root cause: __shfl(ue, src) under "if (ln<16)" sources
// inactive lanes 16..63 -> undefined values -> final user-dot garbage.
// Fix removes the divergence entirely: with A = pre-row-0 broadcast, all
// D rows are identical, so lane ln = lg*16+lq already holds its own dim's
// item value in fa[lg][0] (col = lq). Select fa/bcol by lg (cndmask, static
// indexing), multiply by the lane's own ue, full 64-lane butterfly reduce.
// Everything else = R13: scores via MFMA (R12-verified fragment recipe),
// fp16 LDS tables (38KB), deep hop-2 gather prefetch with post-softmax pins.

namespace {

constexpr int kDim      = 64;
constexpr int kNN       = 8;
constexpr int kNumEnt   = 100000;
constexpr int kItemInKG = 20000;
constexpr int kElems    = 8;     // batch elements (waves) per block
constexpr int kRelChunks = 976;  // 61 rel rows * 16 float4 chunks
constexpr int kP        = 68;    // fp16 row stride (136B)
constexpr size_t kEntHalfBytes = (size_t)(kNumEnt + 1) * kDim * sizeof(__half);

typedef _Float16 f16x4 __attribute__((ext_vector_type(4)));
typedef _Float16 f16x8 __attribute__((ext_vector_type(8)));
typedef float    f32x4 __attribute__((ext_vector_type(4)));

__device__ __forceinline__ float fast_sigmoid(float x) {
  return 1.0f / (1.0f + __expf(-x));
}
__device__ __forceinline__ float fast_tanh(float x) {
  return 2.0f / (1.0f + __expf(-2.0f * x)) - 1.0f;
}
__device__ __forceinline__ float readlane_f(float v, int lane) {
  return __int_as_float(__builtin_amdgcn_readlane(__float_as_int(v), lane));
}
__device__ __forceinline__ f16x8 join8(f16x4 lo, f16x4 hi) {
  return __builtin_shufflevector(lo, hi, 0, 1, 2, 3, 4, 5, 6, 7);
}
__device__ __forceinline__ f16x4 cvt4(float4 f) {
  f16x4 h;
  h[0] = (_Float16)f.x; h[1] = (_Float16)f.y;
  h[2] = (_Float16)f.z; h[3] = (_Float16)f.w;
  return h;
}

// ---- pre-pass: ent_emb fp32 -> fp16 into workspace ----
__global__ void __launch_bounds__(256)
conv_kernel(const float* __restrict__ src, __half2* __restrict__ dst, int n4) {
  const int i = blockIdx.x * 256 + threadIdx.x;
  if (i < n4) {
    const float4 f = reinterpret_cast<const float4*>(src)[i];
    dst[2 * i + 0] = __floats2half2_rn(f.x, f.y);
    dst[2 * i + 1] = __floats2half2_rn(f.z, f.w);
  }
}

template <bool HALF>
__global__ void __launch_bounds__(kElems * 64)
__attribute__((amdgpu_waves_per_eu(4)))
kgcn_kernel(const int* __restrict__ u, const int* __restrict__ v,
            const float* __restrict__ usr_emb, const float* __restrict__ item_emb,
            const float* __restrict__ ent_emb, const __half* __restrict__ ent_h,
            const float* __restrict__ rel_emb,
            const float* __restrict__ W, const float* __restrict__ bias,
            const int* __restrict__ adj_ent, const int* __restrict__ adj_rel,
            float* __restrict__ out)
{
  const int tid = threadIdx.x;
  const int wv  = tid >> 6;
  const int ln  = tid & 63;
  const int lq  = ln & 15;    // MFMA m/n index
  const int lg  = ln >> 4;    // MFMA k-slot group
  const int b   = blockIdx.x * kElems + wv;

  __shared__ __align__(16) _Float16 s_wh[kDim * kP];      // 8,704 B
  __shared__ __align__(16) _Float16 s_relh[kDim * kP];    // 8,704 B
  __shared__ __align__(16) _Float16 s_ueh[kElems * kDim]; // 1,024 B
  __shared__ __align__(16) _Float16 s_pre[72 * kP];       // 9,792 B
  __shared__ __align__(16) _Float16 s_h[72 * kP];         // 9,792 B

  // ---- staging loads (coalesced float4) ----
  const float4* W4 = reinterpret_cast<const float4*>(W);
  const float4* R4 = reinterpret_cast<const float4*>(rel_emb);
  const float4 wst0 = W4[tid];
  const float4 wst1 = W4[512 + tid];
  const float4 rst0 = R4[tid];
  const float4 rst1 = (512 + tid < kRelChunks) ? R4[512 + tid]
                                               : make_float4(0.f, 0.f, 0.f, 0.f);

  // ---- adjacency chain (registers + cross-lane only) ----
  const int   uid = u[b];
  const int   vid = v[b];
  const float ue  = usr_emb[(size_t)uid * kDim + ln];
  const float ev0 = item_emb[(size_t)vid * kDim + ln];
  const int   e0  = (vid >= kItemInKG) ? kNumEnt : vid;   // pad entity

  int e1v = 0, r1v = 0;
  if (ln < kNN) {
    e1v = adj_ent[(size_t)e0 * kNN + ln];
    r1v = adj_rel[(size_t)e0 * kNN + ln];
  }
  const int parent = __shfl(e1v, ln >> 3, 64);   // wave-uniform exec, valid regs
  const int e2v    = adj_ent[(size_t)parent * kNN + (ln & 7)];
  const int r2v    = adj_rel[(size_t)parent * kNN + (ln & 7)];

  // ---- staging writes (fp16 row-major, pad 68) ----
  {
    int id = tid, row = id >> 4, c4 = (id & 15) << 2;
    *reinterpret_cast<f16x4*>(&s_wh[row * kP + c4]) = cvt4(wst0);
    *reinterpret_cast<f16x4*>(&s_relh[row * kP + c4]) = cvt4(rst0);
    id = 512 + tid; row = id >> 4; c4 = (id & 15) << 2;
    *reinterpret_cast<f16x4*>(&s_wh[row * kP + c4]) = cvt4(wst1);
    *reinterpret_cast<f16x4*>(&s_relh[row * kP + c4]) = cvt4(rst1); // 61..63: 0
  }
  s_ueh[wv * kDim + ln] = (_Float16)ue;

  // ---- hop-1 embedding gathers (ids wave-uniform via readlane -> saddr) ----
  float ev1r[kNN];
  #pragma unroll
  for (int m = 0; m < kNN; ++m) {
    const size_t row = (size_t)__builtin_amdgcn_readlane(e1v, m) * kDim + ln;
    ev1r[m] = HALF ? __half2float(ent_h[row]) : ent_emb[row];
  }

  // ---- issue ALL 64 hop-2 fp16 gathers now (pins after softmax) ----
  unsigned int g16[kDim];
  if constexpr (HALF) {
    const unsigned short* eh = reinterpret_cast<const unsigned short*>(ent_h);
    #pragma unroll
    for (int i = 0; i < kDim; ++i) {
      const size_t row = (size_t)__builtin_amdgcn_readlane(e2v, i) * kDim + ln;
      g16[i] = eh[row];
    }
  }

  __syncthreads();   // staging visible

  // ---- scores via MFMA: t[r] = ue . rel[r] (R12-verified recipe) ----
  f16x8 Au[2];
  #pragma unroll
  for (int s = 0; s < 2; ++s) {
    const _Float16* p = &s_ueh[wv * kDim + s * 32 + lg * 4];
    Au[s] = join8(*reinterpret_cast<const f16x4*>(p),
                  *reinterpret_cast<const f16x4*>(p + 16));
  }
  f32x4 ts[4];
  #pragma unroll
  for (int tt = 0; tt < 4; ++tt) {
    ts[tt] = f32x4{0.f, 0.f, 0.f, 0.f};
    #pragma unroll
    for (int s = 0; s < 2; ++s) {
      const _Float16* p = &s_relh[(tt * 16 + lq) * kP + s * 32 + lg * 4];
      const f16x8 Rf = join8(*reinterpret_cast<const f16x4*>(p),
                             *reinterpret_cast<const f16x4*>(p + 16));
      ts[tt] = __builtin_amdgcn_mfma_f32_16x16x32_f16(Au[s], Rf, ts[tt],
                                                      0, 0, 0);
    }
  }
  // t[r] lives on lane (r&15) in ts[r>>4][0] (all D rows identical).
  auto t_lookup = [&](int r) -> float {
    const int sl = r & 15;
    const float c0 = __shfl(ts[0][0], sl, 64);
    const float c1 = __shfl(ts[1][0], sl, 64);
    const float c2 = __shfl(ts[2][0], sl, 64);
    const float c3 = __shfl(ts[3][0], sl, 64);
    const float ab = (r & 16) ? c1 : c0;
    const float cd = (r & 16) ? c3 : c2;
    return (r & 32) ? cd : ab;
  };

  // ---- softmaxes: 8-lane groups {1,2,4} ----
  float w2v;
  {
    const float s2 = t_lookup(r2v);
    float mx = s2;
    #pragma unroll
    for (int m = 1; m <= 4; m <<= 1) mx = fmaxf(mx, __shfl_xor(mx, m, 64));
    const float e = __expf(s2 - mx);
    float sm = e;
    #pragma unroll
    for (int m = 1; m <= 4; m <<= 1) sm += __shfl_xor(sm, m, 64);
    w2v = e / sm;
  }
  float w0v;   // lanes 0..7; reused for iter-1
  {
    const float s0 = t_lookup(r1v);
    float mx = s0;
    #pragma unroll
    for (int m = 1; m <= 4; m <<= 1) mx = fmaxf(mx, __shfl_xor(mx, m, 64));
    w0v = __expf(s0 - mx);
    float sm = w0v;
    #pragma unroll
    for (int m = 1; m <= 4; m <<= 1) sm += __shfl_xor(sm, m, 64);
    w0v /= sm;
  }

  if constexpr (HALF) {
    #pragma unroll
    for (int i = 0; i < kDim; ++i) asm volatile("" : "+v"(g16[i]));
  }

  // ---- aggregation (lane = dim) -> fp16 pre-rows in LDS ----
  {
    float agg = 0.f;
    #pragma unroll
    for (int n = 0; n < kNN; ++n)
      agg = fmaf(readlane_f(w0v, n), ev1r[n], agg);
    s_pre[(wv * 9 + 0) * kP + ln] = (_Float16)(ev0 + agg);
  }
  if constexpr (HALF) {
    #pragma unroll
    for (int m = 0; m < kNN; ++m) {
      float acc = 0.f;
      #pragma unroll
      for (int n = 0; n < kNN; ++n) {
        const float g = __half2float(
            __ushort_as_half((unsigned short)g16[m * kNN + n]));
        acc = fmaf(readlane_f(w2v, m * kNN + n), g, acc);
      }
      s_pre[(wv * 9 + 1 + m) * kP + ln] = (_Float16)(ev1r[m] + acc);
    }
  } else {
    #pragma unroll 2
    for (int m = 0; m < kNN; ++m) {
      float acc = 0.f;
      #pragma unroll
      for (int n = 0; n < kNN; ++n) {
        const size_t row =
            (size_t)__builtin_amdgcn_readlane(e2v, m * kNN + n) * kDim + ln;
        acc = fmaf(readlane_f(w2v, m * kNN + n), ent_emb[row], acc);
      }
      s_pre[(wv * 9 + 1 + m) * kP + ln] = (_Float16)(ev1r[m] + acc);
    }
  }

  // ---- bias cols for this lane's D columns ----
  float bcol[4];
  #pragma unroll
  for (int tt = 0; tt < 4; ++tt) bcol[tt] = bias[tt * 16 + lq];

  // ---- B fragments: W^T, cached once ----
  f16x8 Bf[8];
  #pragma unroll
  for (int tt = 0; tt < 4; ++tt) {
    #pragma unroll
    for (int s = 0; s < 2; ++s) {
      const _Float16* p = &s_wh[(tt * 16 + lq) * kP + s * 32 + lg * 4];
      Bf[tt * 2 + s] = join8(*reinterpret_cast<const f16x4*>(p),
                             *reinterpret_cast<const f16x4*>(p + 16));
    }
  }

  // ---- A fragments (own 9 pre-rows; m = lq, clamped) + main GEMM ----
  const int arow = wv * 9 + (lq < 9 ? lq : 8);
  f16x8 Af[2];
  #pragma unroll
  for (int s = 0; s < 2; ++s) {
    const _Float16* p = &s_pre[arow * kP + s * 32 + lg * 4];
    Af[s] = join8(*reinterpret_cast<const f16x4*>(p),
                  *reinterpret_cast<const f16x4*>(p + 16));
  }
  f32x4 acc[4];
  #pragma unroll
  for (int tt = 0; tt < 4; ++tt) acc[tt] = f32x4{0.f, 0.f, 0.f, 0.f};
  #pragma unroll
  for (int tt = 0; tt < 4; ++tt)
    #pragma unroll
    for (int s = 0; s < 2; ++s)
      acc[tt] = __builtin_amdgcn_mfma_f32_16x16x32_f16(Af[s], Bf[tt * 2 + s],
                                                       acc[tt], 0, 0, 0);

  // ---- h = sigmoid(acc + b): D row=(lg*4+r)=vec, col=tt*16+lq ----
  #pragma unroll
  for (int tt = 0; tt < 4; ++tt) {
    #pragma unroll
    for (int r = 0; r < 4; ++r) {
      const int vec = lg * 4 + r;
      if (vec < 9)
        s_h[(wv * 9 + vec) * kP + tt * 16 + lq] =
            (_Float16)fast_sigmoid(acc[tt][r] + bcol[tt]);
    }
  }

  // ---- iter-1 hop-0 (reuse w0), lane = dim; overwrite pre-row 0 ----
  {
    float pre = (float)s_h[(wv * 9 + 0) * kP + ln];
    #pragma unroll
    for (int n = 0; n < kNN; ++n)
      pre = fmaf(readlane_f(w0v, n), (float)s_h[(wv * 9 + 1 + n) * kP + ln],
                 pre);
    s_pre[(wv * 9 + 0) * kP + ln] = (_Float16)pre;
  }

  // ---- final matvec via MFMA: A = pre-row 0 broadcast (uniform read) ----
  f16x8 Ff[2];
  #pragma unroll
  for (int s = 0; s < 2; ++s) {
    const _Float16* p = &s_pre[(wv * 9 + 0) * kP + s * 32 + lg * 4];
    Ff[s] = join8(*reinterpret_cast<const f16x4*>(p),
                  *reinterpret_cast<const f16x4*>(p + 16));
  }
  f32x4 fa[4];
  #pragma unroll
  for (int tt = 0; tt < 4; ++tt) fa[tt] = f32x4{0.f, 0.f, 0.f, 0.f};
  #pragma unroll
  for (int tt = 0; tt < 4; ++tt)
    #pragma unroll
    for (int s = 0; s < 2; ++s)
      fa[tt] = __builtin_amdgcn_mfma_f32_16x16x32_f16(Ff[s], Bf[tt * 2 + s],
                                                      fa[tt], 0, 0, 0);

  // ---- epilogue (R13 bugfix): all D rows identical, so lane ln = lg*16+lq
  // already holds item[ln] in fa[lg][0] (its col = lq). Static-index select
  // by lg (cndmask), multiply by OWN ue, full-wave butterfly. No divergence,
  // no cross-lane ue fetch.
  {
    float fown = fa[0][0], bown = bcol[0];
    if (lg == 1) { fown = fa[1][0]; bown = bcol[1]; }
    if (lg == 2) { fown = fa[2][0]; bown = bcol[2]; }
    if (lg == 3) { fown = fa[3][0]; bown = bcol[3]; }
    float part = fast_tanh(fown + bown) * ue;
    #pragma unroll
    for (int off = 32; off > 0; off >>= 1)
      part += __shfl_xor(part, off, 64);
    if (ln == 0) out[b] = fast_sigmoid(part);
  }
}

}  // namespace

extern "C" void kernel_launch(void* const* d_in, const int* in_sizes, int n_in,
                              void* d_out, int out_size, void* d_ws, size_t ws_size,
                              hipStream_t stream) {
  const int*   u        = (const int*)d_in[0];
  const int*   v        = (const int*)d_in[1];
  const float* usr_emb  = (const float*)d_in[2];
  const float* item_emb = (const float*)d_in[3];
  const float* ent_emb  = (const float*)d_in[4];
  const float* rel_emb  = (const float*)d_in[5];
  const float* W        = (const float*)d_in[6];
  const float* bias     = (const float*)d_in[7];
  const int*   adj_ent  = (const int*)d_in[8];
  const int*   adj_rel  = (const int*)d_in[9];
  float*       out      = (float*)d_out;

  const int B = in_sizes[0];   // 16384, divisible by kElems=8
  dim3 grid(B / kElems), block(kElems * 64);

  const bool use_half = (ws_size >= kEntHalfBytes);
  if (use_half) {
    __half* ent_h = (__half*)d_ws;
    const int n4 = (kNumEnt + 1) * kDim / 4;
    hipLaunchKernelGGL(conv_kernel, dim3((n4 + 255) / 256), dim3(256), 0,
                       stream, ent_emb, (__half2*)ent_h, n4);
    hipLaunchKernelGGL((kgcn_kernel<true>), grid, block, 0, stream,
                       u, v, usr_emb, item_emb, ent_emb, ent_h, rel_emb, W,
                       bias, adj_ent, adj_rel, out);
  } else {
    hipLaunchKernelGGL((kgcn_kernel<false>), grid, block, 0, stream,
                       u, v, usr_emb, item_emb, ent_emb, (const __half*)d_ws,
                       rel_emb, W, bias, adj_ent, adj_rel, out);
  }
}

// Round 15
// 52.287 us; speedup vs baseline: 1.5669x; 1.0017x over previous
//
#include <hip/hip_runtime.h>
#include <hip/hip_fp16.h>

// KGCN forward, MI355X. R15 = R14 + scalarized adjacency + LDS-w2 broadcast.
// R14 audit: ~250 of ~850 VALU issues/wave are plumbing (64 readlane + 64
// addr-mads for g16, 64 readlane for w2, cvts). The whole adjacency tree is
// wave-uniform (b -> v[b] -> adj(e0) -> adj(e1[m])) -> readfirstlane(b) makes
// it s_load chains into SGPRs; gather addresses become saddr-form (SALU pipe,
// co-issues with VALU). w2 broadcasts move to the ~25%-busy LDS pipe
// (same-address reads = conflict-free). MFMA paths untouched (R12/R14
// verified). Gates: SGPR_Count must jump to ~80-102, else scalarization
// failed; conflicts must stay ~0.

namespace {

constexpr int kDim      = 64;
constexpr int kNN       = 8;
constexpr int kNumEnt   = 100000;
constexpr int kItemInKG = 20000;
constexpr int kElems    = 8;     // batch elements (waves) per block
constexpr int kRelChunks = 976;  // 61 rel rows * 16 float4 chunks
constexpr int kP        = 68;    // fp16 row stride (136B)
constexpr size_t kEntHalfBytes = (size_t)(kNumEnt + 1) * kDim * sizeof(__half);

typedef _Float16 f16x4 __attribute__((ext_vector_type(4)));
typedef _Float16 f16x8 __attribute__((ext_vector_type(8)));
typedef float    f32x4 __attribute__((ext_vector_type(4)));

__device__ __forceinline__ float fast_sigmoid(float x) {
  return 1.0f / (1.0f + __expf(-x));
}
__device__ __forceinline__ float fast_tanh(float x) {
  return 2.0f / (1.0f + __expf(-2.0f * x)) - 1.0f;
}
__device__ __forceinline__ float readlane_f(float v, int lane) {
  return __int_as_float(__builtin_amdgcn_readlane(__float_as_int(v), lane));
}
__device__ __forceinline__ f16x8 join8(f16x4 lo, f16x4 hi) {
  return __builtin_shufflevector(lo, hi, 0, 1, 2, 3, 4, 5, 6, 7);
}
__device__ __forceinline__ f16x4 cvt4(float4 f) {
  f16x4 h;
  h[0] = (_Float16)f.x; h[1] = (_Float16)f.y;
  h[2] = (_Float16)f.z; h[3] = (_Float16)f.w;
  return h;
}

// ---- pre-pass: ent_emb fp32 -> fp16 into workspace ----
__global__ void __launch_bounds__(256)
conv_kernel(const float* __restrict__ src, __half2* __restrict__ dst, int n4) {
  const int i = blockIdx.x * 256 + threadIdx.x;
  if (i < n4) {
    const float4 f = reinterpret_cast<const float4*>(src)[i];
    dst[2 * i + 0] = __floats2half2_rn(f.x, f.y);
    dst[2 * i + 1] = __floats2half2_rn(f.z, f.w);
  }
}

template <bool HALF>
__global__ void __launch_bounds__(kElems * 64)
__attribute__((amdgpu_waves_per_eu(4)))
kgcn_kernel(const int* __restrict__ u, const int* __restrict__ v,
            const float* __restrict__ usr_emb, const float* __restrict__ item_emb,
            const float* __restrict__ ent_emb, const __half* __restrict__ ent_h,
            const float* __restrict__ rel_emb,
            const float* __restrict__ W, const float* __restrict__ bias,
            const int* __restrict__ adj_ent, const int* __restrict__ adj_rel,
            float* __restrict__ out)
{
  const int tid = threadIdx.x;
  const int wv  = tid >> 6;
  const int ln  = tid & 63;
  const int lq  = ln & 15;    // MFMA m/n index
  const int lg  = ln >> 4;    // MFMA k-slot group
  const int b   = blockIdx.x * kElems + wv;

  __shared__ __align__(16) _Float16 s_wh[kDim * kP];      // 8,704 B
  __shared__ __align__(16) _Float16 s_relh[kDim * kP];    // 8,704 B
  __shared__ __align__(16) _Float16 s_ueh[kElems * kDim]; // 1,024 B
  __shared__ __align__(16) _Float16 s_pre[72 * kP];       // 9,792 B
  __shared__ __align__(16) _Float16 s_h[72 * kP];         // 9,792 B
  __shared__ float s_w2[kElems][kDim];                    // 2,048 B

  // ---- staging loads (coalesced float4) ----
  const float4* W4 = reinterpret_cast<const float4*>(W);
  const float4* R4 = reinterpret_cast<const float4*>(rel_emb);
  const float4 wst0 = W4[tid];
  const float4 wst1 = W4[512 + tid];
  const float4 rst0 = R4[tid];
  const float4 rst1 = (512 + tid < kRelChunks) ? R4[512 + tid]
                                               : make_float4(0.f, 0.f, 0.f, 0.f);

  // ---- adjacency chain, SCALARIZED: b is wave-uniform -> force SGPR and
  // let the whole id tree ride the SALU/s_load path.
  const int bs    = __builtin_amdgcn_readfirstlane(b);
  const int uid_s = u[bs];                                   // s_load
  const int vid_s = v[bs];                                   // s_load
  const int e0s   = (vid_s >= kItemInKG) ? kNumEnt : vid_s;  // pad entity

  const float ue  = usr_emb[(size_t)uid_s * kDim + ln];      // saddr vec load
  const float ev0 = item_emb[(size_t)vid_s * kDim + ln];

  int e1s[kNN];
  {
    const int* __restrict__ a0 = adj_ent + (size_t)e0s * kNN;
    #pragma unroll
    for (int m = 0; m < kNN; ++m) e1s[m] = a0[m];            // s_load x8
  }
  int e2s[kDim];
  #pragma unroll
  for (int m = 0; m < kNN; ++m) {
    const int* __restrict__ am = adj_ent + (size_t)e1s[m] * kNN;
    #pragma unroll
    for (int n = 0; n < kNN; ++n) e2s[m * kNN + n] = am[n];  // s_load x8 each
  }
  // per-lane relation ids (vector; feed the per-lane softmax)
  int r1v = 0;
  if (ln < kNN) r1v = adj_rel[(size_t)e0s * kNN + ln];
  int parent = e1s[0];
  #pragma unroll
  for (int m = 1; m < kNN; ++m)
    parent = ((ln >> 3) == m) ? e1s[m] : parent;   // SGPR select by lane group
  const int r2v = adj_rel[(size_t)parent * kNN + (ln & 7)];

  // ---- staging writes (fp16 row-major, pad 68) ----
  {
    int id = tid, row = id >> 4, c4 = (id & 15) << 2;
    *reinterpret_cast<f16x4*>(&s_wh[row * kP + c4]) = cvt4(wst0);
    *reinterpret_cast<f16x4*>(&s_relh[row * kP + c4]) = cvt4(rst0);
    id = 512 + tid; row = id >> 4; c4 = (id & 15) << 2;
    *reinterpret_cast<f16x4*>(&s_wh[row * kP + c4]) = cvt4(wst1);
    *reinterpret_cast<f16x4*>(&s_relh[row * kP + c4]) = cvt4(rst1); // 61..63: 0
  }
  s_ueh[wv * kDim + ln] = (_Float16)ue;

  // ---- hop-1 embedding gathers (SGPR ids -> saddr loads) ----
  float ev1r[kNN];
  #pragma unroll
  for (int m = 0; m < kNN; ++m) {
    const size_t row = (size_t)e1s[m] * kDim + ln;
    ev1r[m] = HALF ? __half2float(ent_h[row]) : ent_emb[row];
  }

  // ---- issue ALL 64 hop-2 fp16 gathers now (SGPR ids -> saddr, zero VALU
  // address math; pins after softmax keep them un-sinkable).
  unsigned short g16[kDim];
  if constexpr (HALF) {
    const unsigned short* eh = reinterpret_cast<const unsigned short*>(ent_h);
    #pragma unroll
    for (int i = 0; i < kDim; ++i)
      g16[i] = eh[(size_t)e2s[i] * kDim + ln];
  }

  __syncthreads();   // staging visible

  // ---- scores via MFMA: t[r] = ue . rel[r] (R12-verified recipe) ----
  f16x8 Au[2];
  #pragma unroll
  for (int s = 0; s < 2; ++s) {
    const _Float16* p = &s_ueh[wv * kDim + s * 32 + lg * 4];
    Au[s] = join8(*reinterpret_cast<const f16x4*>(p),
                  *reinterpret_cast<const f16x4*>(p + 16));
  }
  f32x4 ts[4];
  #pragma unroll
  for (int tt = 0; tt < 4; ++tt) {
    ts[tt] = f32x4{0.f, 0.f, 0.f, 0.f};
    #pragma unroll
    for (int s = 0; s < 2; ++s) {
      const _Float16* p = &s_relh[(tt * 16 + lq) * kP + s * 32 + lg * 4];
      const f16x8 Rf = join8(*reinterpret_cast<const f16x4*>(p),
                             *reinterpret_cast<const f16x4*>(p + 16));
      ts[tt] = __builtin_amdgcn_mfma_f32_16x16x32_f16(Au[s], Rf, ts[tt],
                                                      0, 0, 0);
    }
  }
  // t[r] lives on lane (r&15) in ts[r>>4][0] (all D rows identical).
  auto t_lookup = [&](int r) -> float {
    const int sl = r & 15;
    const float c0 = __shfl(ts[0][0], sl, 64);
    const float c1 = __shfl(ts[1][0], sl, 64);
    const float c2 = __shfl(ts[2][0], sl, 64);
    const float c3 = __shfl(ts[3][0], sl, 64);
    const float ab = (r & 16) ? c1 : c0;
    const float cd = (r & 16) ? c3 : c2;
    return (r & 32) ? cd : ab;
  };

  // ---- softmaxes: 8-lane groups {1,2,4} ----
  {
    const float s2 = t_lookup(r2v);
    float mx = s2;
    #pragma unroll
    for (int m = 1; m <= 4; m <<= 1) mx = fmaxf(mx, __shfl_xor(mx, m, 64));
    const float e = __expf(s2 - mx);
    float sm = e;
    #pragma unroll
    for (int m = 1; m <= 4; m <<= 1) sm += __shfl_xor(sm, m, 64);
    s_w2[wv][ln] = e / sm;   // broadcast via LDS (same-addr reads are free)
  }
  float w0v;   // lanes 0..7; reused for iter-1
  {
    const float s0 = t_lookup(r1v);
    float mx = s0;
    #pragma unroll
    for (int m = 1; m <= 4; m <<= 1) mx = fmaxf(mx, __shfl_xor(mx, m, 64));
    w0v = __expf(s0 - mx);
    float sm = w0v;
    #pragma unroll
    for (int m = 1; m <= 4; m <<= 1) sm += __shfl_xor(sm, m, 64);
    w0v /= sm;
  }

  if constexpr (HALF) {
    #pragma unroll
    for (int i = 0; i < kDim; ++i) asm volatile("" : "+v"(g16[i]));
  }

  // ---- aggregation (lane = dim) -> fp16 pre-rows in LDS ----
  {
    float agg = 0.f;
    #pragma unroll
    for (int n = 0; n < kNN; ++n)
      agg = fmaf(readlane_f(w0v, n), ev1r[n], agg);
    s_pre[(wv * 9 + 0) * kP + ln] = (_Float16)(ev0 + agg);
  }
  if constexpr (HALF) {
    #pragma unroll
    for (int m = 0; m < kNN; ++m) {
      float acc = 0.f;
      #pragma unroll
      for (int n = 0; n < kNN; ++n) {
        // (float)f16 * f32 + f32 -> v_fma_mix candidate; w2 from LDS
        const _Float16 hv =
            __builtin_bit_cast(_Float16, g16[m * kNN + n]);
        acc = fmaf((float)hv, s_w2[wv][m * kNN + n], acc);
      }
      s_pre[(wv * 9 + 1 + m) * kP + ln] = (_Float16)(ev1r[m] + acc);
    }
  } else {
    #pragma unroll 2
    for (int m = 0; m < kNN; ++m) {
      float acc = 0.f;
      #pragma unroll
      for (int n = 0; n < kNN; ++n) {
        const size_t row = (size_t)e2s[m * kNN + n] * kDim + ln;
        acc = fmaf(s_w2[wv][m * kNN + n], ent_emb[row], acc);
      }
      s_pre[(wv * 9 + 1 + m) * kP + ln] = (_Float16)(ev1r[m] + acc);
    }
  }

  // ---- bias cols for this lane's D columns ----
  float bcol[4];
  #pragma unroll
  for (int tt = 0; tt < 4; ++tt) bcol[tt] = bias[tt * 16 + lq];

  // ---- B fragments: W^T, cached once ----
  f16x8 Bf[8];
  #pragma unroll
  for (int tt = 0; tt < 4; ++tt) {
    #pragma unroll
    for (int s = 0; s < 2; ++s) {
      const _Float16* p = &s_wh[(tt * 16 + lq) * kP + s * 32 + lg * 4];
      Bf[tt * 2 + s] = join8(*reinterpret_cast<const f16x4*>(p),
                             *reinterpret_cast<const f16x4*>(p + 16));
    }
  }

  // ---- A fragments (own 9 pre-rows; m = lq, clamped) + main GEMM ----
  const int arow = wv * 9 + (lq < 9 ? lq : 8);
  f16x8 Af[2];
  #pragma unroll
  for (int s = 0; s < 2; ++s) {
    const _Float16* p = &s_pre[arow * kP + s * 32 + lg * 4];
    Af[s] = join8(*reinterpret_cast<const f16x4*>(p),
                  *reinterpret_cast<const f16x4*>(p + 16));
  }
  f32x4 acc[4];
  #pragma unroll
  for (int tt = 0; tt < 4; ++tt) acc[tt] = f32x4{0.f, 0.f, 0.f, 0.f};
  #pragma unroll
  for (int tt = 0; tt < 4; ++tt)
    #pragma unroll
    for (int s = 0; s < 2; ++s)
      acc[tt] = __builtin_amdgcn_mfma_f32_16x16x32_f16(Af[s], Bf[tt * 2 + s],
                                                       acc[tt], 0, 0, 0);

  // ---- h = sigmoid(acc + b): D row=(lg*4+r)=vec, col=tt*16+lq ----
  #pragma unroll
  for (int tt = 0; tt < 4; ++tt) {
    #pragma unroll
    for (int r = 0; r < 4; ++r) {
      const int vec = lg * 4 + r;
      if (vec < 9)
        s_h[(wv * 9 + vec) * kP + tt * 16 + lq] =
            (_Float16)fast_sigmoid(acc[tt][r] + bcol[tt]);
    }
  }

  // ---- iter-1 hop-0 (reuse w0), lane = dim; overwrite pre-row 0 ----
  {
    float pre = (float)s_h[(wv * 9 + 0) * kP + ln];
    #pragma unroll
    for (int n = 0; n < kNN; ++n)
      pre = fmaf(readlane_f(w0v, n), (float)s_h[(wv * 9 + 1 + n) * kP + ln],
                 pre);
    s_pre[(wv * 9 + 0) * kP + ln] = (_Float16)pre;
  }

  // ---- final matvec via MFMA: A = pre-row 0 broadcast (uniform read) ----
  f16x8 Ff[2];
  #pragma unroll
  for (int s = 0; s < 2; ++s) {
    const _Float16* p = &s_pre[(wv * 9 + 0) * kP + s * 32 + lg * 4];
    Ff[s] = join8(*reinterpret_cast<const f16x4*>(p),
                  *reinterpret_cast<const f16x4*>(p + 16));
  }
  f32x4 fa[4];
  #pragma unroll
  for (int tt = 0; tt < 4; ++tt) fa[tt] = f32x4{0.f, 0.f, 0.f, 0.f};
  #pragma unroll
  for (int tt = 0; tt < 4; ++tt)
    #pragma unroll
    for (int s = 0; s < 2; ++s)
      fa[tt] = __builtin_amdgcn_mfma_f32_16x16x32_f16(Ff[s], Bf[tt * 2 + s],
                                                      fa[tt], 0, 0, 0);

  // ---- epilogue (R14-verified): lane ln = lg*16+lq holds item[ln] in
  // fa[lg][0]; static-index select, multiply by own ue, butterfly reduce.
  {
    float fown = fa[0][0], bown = bcol[0];
    if (lg == 1) { fown = fa[1][0]; bown = bcol[1]; }
    if (lg == 2) { fown = fa[2][0]; bown = bcol[2]; }
    if (lg == 3) { fown = fa[3][0]; bown = bcol[3]; }
    float part = fast_tanh(fown + bown) * ue;
    #pragma unroll
    for (int off = 32; off > 0; off >>= 1)
      part += __shfl_xor(part, off, 64);
    if (ln == 0) out[b] = fast_sigmoid(part);
  }
}

}  // namespace

extern "C" void kernel_launch(void* const* d_in, const int* in_sizes, int n_in,
                              void* d_out, int out_size, void* d_ws, size_t ws_size,
                              hipStream_t stream) {
  const int*   u        = (const int*)d_in[0];
  const int*   v        = (const int*)d_in[1];
  const float* usr_emb  = (const float*)d_in[2];
  const float* item_emb = (const float*)d_in[3];
  const float* ent_emb  = (const float*)d_in[4];
  const float* rel_emb  = (const float*)d_in[5];
  const float* W        = (const float*)d_in[6];
  const float* bias     = (const float*)d_in[7];
  const int*   adj_ent  = (const int*)d_in[8];
  const int*   adj_rel  = (const int*)d_in[9];
  float*       out      = (float*)d_out;

  const int B = in_sizes[0];   // 16384, divisible by kElems=8
  dim3 grid(B / kElems), block(kElems * 64);

  const bool use_half = (ws_size >= kEntHalfBytes);
  if (use_half) {
    __half* ent_h = (__half*)d_ws;
    const int n4 = (kNumEnt + 1) * kDim / 4;
    hipLaunchKernelGGL(conv_kernel, dim3((n4 + 255) / 256), dim3(256), 0,
                       stream, ent_emb, (__half2*)ent_h, n4);
    hipLaunchKernelGGL((kgcn_kernel<true>), grid, block, 0, stream,
                       u, v, usr_emb, item_emb, ent_emb, ent_h, rel_emb, W,
                       bias, adj_ent, adj_rel, out);
  } else {
    hipLaunchKernelGGL((kgcn_kernel<false>), grid, block, 0, stream,
                       u, v, usr_emb, item_emb, ent_emb, (const __half*)d_ws,
                       rel_emb, W, bias, adj_ent, adj_rel, out);
  }
}